// Round 7
// baseline (343.858 us; speedup 1.0000x reference)
//
#include <hip/hip_runtime.h>
#include <hip/hip_bf16.h>

typedef __bf16 bf16_t;
typedef __attribute__((ext_vector_type(8))) __bf16 bf16x8;
typedef __attribute__((ext_vector_type(4))) __bf16 bf16x4;
typedef __attribute__((ext_vector_type(4))) float f32x4;

#define QSCALE 0.1803368801111204f  /* 0.125 * log2(e) */

// async global->LDS, 16B per lane; LDS dst = wave-uniform base + lane*16
static __device__ inline void glds16(const bf16_t* g, bf16_t* l) {
    __builtin_amdgcn_global_load_lds(
        (__attribute__((address_space(1))) const void*)g,
        (__attribute__((address_space(3))) void*)l,
        16, 0, 0);
}

// ---------------------------------------------------------------------------
__global__ void cvt_kernel(const float* __restrict__ in, bf16_t* __restrict__ out, int n4) {
    int i = blockIdx.x * 256 + threadIdx.x;
    if (i < n4) {
        float4 v = ((const float4*)in)[i];
        bf16x4 o = {(bf16_t)v.x, (bf16_t)v.y, (bf16_t)v.z, (bf16_t)v.w};
        ((bf16x4*)out)[i] = o;
    }
}

__global__ void zero_f4(float4* __restrict__ p, int n4) {
    int i = blockIdx.x * 256 + threadIdx.x;
    if (i < n4) p[i] = {0.f, 0.f, 0.f, 0.f};
}

// ---------------------------------------------------------------------------
// Patch-embed GEMM: tok[4096,768] = patches[4096,256] @ proj_w[768,256]^T + b
// ---------------------------------------------------------------------------
__global__ __launch_bounds__(256) void patch_gemm(const float* __restrict__ x,
                                                  const bf16_t* __restrict__ pw,
                                                  const float* __restrict__ pb,
                                                  float* __restrict__ tok) {
    const int bm = blockIdx.x;
    const int bn = blockIdx.y;
    const int tid = threadIdx.x;

    __shared__ bf16_t At[64][264];
    __shared__ bf16_t Bt[64][264];

    #pragma unroll
    for (int t = 0; t < 16; t++) {
        int linear = tid + t * 256;
        int ml = linear >> 6;
        int kv = (linear & 63) << 2;
        int n = bm * 64 + ml;
        int pr = n >> 6, pc = n & 63;
        int i = kv >> 4, j = kv & 15;
        float4 v = *(const float4*)(x + (pr * 16 + i) * 1024 + pc * 16 + j);
        bf16x4 o = {(bf16_t)v.x, (bf16_t)v.y, (bf16_t)v.z, (bf16_t)v.w};
        *(bf16x4*)(&At[ml][kv]) = o;
    }
    #pragma unroll
    for (int t = 0; t < 8; t++) {
        int linear = tid + t * 256;
        int nl = linear >> 5;
        int kv = (linear & 31) << 3;
        *(int4*)(&Bt[nl][kv]) = *(const int4*)(pw + (size_t)(bn * 64 + nl) * 256 + kv);
    }
    __syncthreads();

    const int lane = tid & 63, wid = tid >> 6, ln = lane & 15, quad = lane >> 4;
    f32x4 acc[4];
    #pragma unroll
    for (int s = 0; s < 4; s++) acc[s] = {0.f, 0.f, 0.f, 0.f};

    #pragma unroll
    for (int kk = 0; kk < 8; kk++) {
        bf16x8 af = *(const bf16x8*)(&At[wid * 16 + ln][kk * 32 + quad * 8]);
        #pragma unroll
        for (int s = 0; s < 4; s++) {
            bf16x8 bfr = *(const bf16x8*)(&Bt[s * 16 + ln][kk * 32 + quad * 8]);
            acc[s] = __builtin_amdgcn_mfma_f32_16x16x32_bf16(af, bfr, acc[s], 0, 0, 0);
        }
    }

    #pragma unroll
    for (int s = 0; s < 4; s++) {
        int e = bn * 64 + s * 16 + ln;
        float bias = pb[e];
        #pragma unroll
        for (int r = 0; r < 4; r++) {
            int m = bm * 64 + wid * 16 + quad * 4 + r;
            tok[(size_t)m * 768 + e] = acc[s][r] + bias;
        }
    }
}

// ---------------------------------------------------------------------------
// LayerNorm per token (768), fp32 stats, bf16 out.
// ---------------------------------------------------------------------------
__global__ __launch_bounds__(256) void ln_kernel(const float* __restrict__ tok,
                                                 const float* __restrict__ g,
                                                 const float* __restrict__ b,
                                                 bf16_t* __restrict__ out) {
    const int n = blockIdx.x;
    const int tid = threadIdx.x;
    const float* row = tok + (size_t)n * 768;
    float x0 = row[tid], x1 = row[tid + 256], x2 = row[tid + 512];
    float s = x0 + x1 + x2;
    float s2 = x0 * x0 + x1 * x1 + x2 * x2;
    #pragma unroll
    for (int off = 32; off; off >>= 1) {
        s += __shfl_xor(s, off);
        s2 += __shfl_xor(s2, off);
    }
    __shared__ float ws1[4], ws2[4];
    int wid = tid >> 6;
    if ((tid & 63) == 0) { ws1[wid] = s; ws2[wid] = s2; }
    __syncthreads();
    s = ws1[0] + ws1[1] + ws1[2] + ws1[3];
    s2 = ws2[0] + ws2[1] + ws2[2] + ws2[3];
    float mu = s * (1.f / 768.f);
    float var = s2 * (1.f / 768.f) - mu * mu;
    float r = rsqrtf(var + 1e-6f);
    bf16_t* orow = out + (size_t)n * 768;
    orow[tid]       = (bf16_t)((x0 - mu) * r * g[tid]       + b[tid]);
    orow[tid + 256] = (bf16_t)((x1 - mu) * r * g[tid + 256] + b[tid + 256]);
    orow[tid + 512] = (bf16_t)((x2 - mu) * r * g[tid + 512] + b[tid + 512]);
}

// ---------------------------------------------------------------------------
// QKV GEMM. Epilogue scatter (per 64-key tile blobs, 8 KB each):
//   q -> qb[12][4096][64], pre-scaled by QSCALE
//   k -> kswz: (h,kt64) tile; elem (sb,half,l,j) =
//        K[key=kt*64+sb*16+(l&15)][dim=half*32+(l>>4)*8+j]
//   v -> vswz: (h,kt64) tile; elem ((mm*4+db),l,jp) =
//        V[key=kt*64+(2mm+(jp>>2))*16+(l>>4)*4+(jp&3)][d=db*16+(l&15)]
// ---------------------------------------------------------------------------
__global__ __launch_bounds__(256) void qkv_gemm(const bf16_t* __restrict__ tokb,
                                                const bf16_t* __restrict__ wq,
                                                bf16_t* __restrict__ qb,
                                                bf16_t* __restrict__ kswz,
                                                bf16_t* __restrict__ vswz) {
    const int bm = blockIdx.x;
    const int bn = blockIdx.y;
    const int tid = threadIdx.x;

    __shared__ bf16_t At[64][72];
    __shared__ bf16_t Bt[64][72];

    const int rl = tid >> 3;
    const int c8 = (tid & 7) * 8;
    const int lane = tid & 63, wid = tid >> 6, ln = lane & 15, quad = lane >> 4;

    f32x4 acc[4];
    #pragma unroll
    for (int s = 0; s < 4; s++) acc[s] = {0.f, 0.f, 0.f, 0.f};

    for (int kb0 = 0; kb0 < 768; kb0 += 64) {
        __syncthreads();
        #pragma unroll
        for (int p = 0; p < 2; p++) {
            int row = rl + p * 32;
            *(int4*)(&At[row][c8]) = *(const int4*)(tokb + (size_t)(bm * 64 + row) * 768 + kb0 + c8);
            *(int4*)(&Bt[row][c8]) = *(const int4*)(wq   + (size_t)(bn * 64 + row) * 768 + kb0 + c8);
        }
        __syncthreads();
        #pragma unroll
        for (int kk = 0; kk < 2; kk++) {
            bf16x8 af = *(const bf16x8*)(&At[wid * 16 + ln][kk * 32 + quad * 8]);
            #pragma unroll
            for (int s = 0; s < 4; s++) {
                bf16x8 bfr = *(const bf16x8*)(&Bt[s * 16 + ln][kk * 32 + quad * 8]);
                acc[s] = __builtin_amdgcn_mfma_f32_16x16x32_bf16(af, bfr, acc[s], 0, 0, 0);
            }
        }
    }

    const int ncol0 = bn * 64;
    const int sidx = ncol0 / 768;
    const int head = (ncol0 % 768) >> 6;
    #pragma unroll
    for (int s = 0; s < 4; s++) {
        int dc = s * 16 + ln;
        #pragma unroll
        for (int r = 0; r < 4; r++) {
            int m = bm * 64 + wid * 16 + quad * 4 + r;   // token index = key
            if (sidx == 0) {
                qb[((size_t)(head * 4096 + m)) * 64 + dc] = (bf16_t)(acc[s][r] * QSCALE);
            } else if (sidx == 1) {
                bf16_t val = (bf16_t)acc[s][r];
                int kt = m >> 6, sb = (m >> 4) & 3, lnk = m & 15;
                int half = dc >> 5, quadk = (dc >> 3) & 3, j = dc & 7;
                int l = quadk * 16 + lnk;
                kswz[((size_t)(head * 64 + kt)) * 4096 + sb * 1024 + half * 512 + l * 8 + j] = val;
            } else {
                bf16_t val = (bf16_t)acc[s][r];
                int kt = m >> 6, keyl = m & 63;
                int sblk = keyl >> 4;
                int mm = sblk >> 1, tb = sblk & 1;
                int w16 = keyl & 15, qv = w16 >> 2, jj = w16 & 3;
                int jp = tb * 4 + jj;
                int db = dc >> 4, lnv = dc & 15;
                int l = qv * 16 + lnv;
                vswz[((size_t)(head * 64 + kt)) * 4096 + ((mm * 4 + db) * 64 + l) * 8 + jp] = val;
            }
        }
    }
}

// ---------------------------------------------------------------------------
// Attention v6, split-K: block = (128 q-tile, head, key-chunk of 1024).
// 256 threads = 4 waves x 32 q. 16 x 64-key tiles per chunk, async
// double-buffered via global_load_lds (vmcnt(4) + raw barriers).
// Unnormalized O and l accumulated into global f32 via atomicAdd.
// Grid: (32, 12, 4).
// ---------------------------------------------------------------------------
__global__ __launch_bounds__(256, 2) void attn_partial(const bf16_t* __restrict__ qbuf,
                                                       const bf16_t* __restrict__ kswz,
                                                       const bf16_t* __restrict__ vswz,
                                                       float* __restrict__ out_raw,
                                                       float* __restrict__ l_acc) {
    const int h = blockIdx.y;
    const int chunk = blockIdx.z;
    const int tid = threadIdx.x;
    const int wid = tid >> 6;           // 0..3
    const int lane = tid & 63;
    const int ln = lane & 15, quad = lane >> 4;
    const int q0 = blockIdx.x * 128;

    __shared__ bf16_t Kf[2][4096];
    __shared__ bf16_t Vf[2][4096];

    // Q B-frags for this wave's two 16-query groups
    bf16x8 qf[2][2];
    #pragma unroll
    for (int g = 0; g < 2; g++) {
        const int q0g = q0 + wid * 32 + g * 16;
        const bf16_t* qrow = qbuf + ((size_t)h * 4096 + q0g + ln) * 64;
        qf[g][0] = *(const bf16x8*)(qrow + quad * 8);
        qf[g][1] = *(const bf16x8*)(qrow + 32 + quad * 8);
    }

    const bf16_t* kg = kswz + (size_t)h * 64 * 4096 + (size_t)chunk * 16 * 4096;
    const bf16_t* vg = vswz + (size_t)h * 64 * 4096 + (size_t)chunk * 16 * 4096;

    f32x4 accO[2][4];
    float l_ln[2] = {0.f, 0.f};
    #pragma unroll
    for (int g = 0; g < 2; g++)
        #pragma unroll
        for (int d = 0; d < 4; d++) accO[g][d] = {0.f, 0.f, 0.f, 0.f};

    // stage one 8KB K + 8KB V tile; 4 waves cover it: 2 K + 2 V glds per wave
    auto stage = [&](int tile, int buf) {
        const bf16_t* kt_g = kg + (size_t)tile * 4096;
        const bf16_t* vt_g = vg + (size_t)tile * 4096;
        #pragma unroll
        for (int i = 0; i < 2; i++) {
            glds16(kt_g + wid * 1024 + i * 512 + lane * 8, &Kf[buf][wid * 1024 + i * 512]);
            glds16(vt_g + wid * 1024 + i * 512 + lane * 8, &Vf[buf][wid * 1024 + i * 512]);
        }
    };

    auto compute = [&](const bf16_t* Kb, const bf16_t* Vb) {
        #pragma unroll
        for (int m = 0; m < 2; m++) {        // m-pair = 32 keys
            bf16x8 vf[4];
            #pragma unroll
            for (int db = 0; db < 4; db++)
                vf[db] = *(const bf16x8*)(Vb + m * 2048 + db * 512 + lane * 8);
            bf16x8 kfa0 = *(const bf16x8*)(Kb + (2 * m) * 1024 + lane * 8);
            bf16x8 kfa1 = *(const bf16x8*)(Kb + (2 * m) * 1024 + 512 + lane * 8);
            bf16x8 kfb0 = *(const bf16x8*)(Kb + (2 * m + 1) * 1024 + lane * 8);
            bf16x8 kfb1 = *(const bf16x8*)(Kb + (2 * m + 1) * 1024 + 512 + lane * 8);
            #pragma unroll
            for (int g = 0; g < 2; g++) {
                f32x4 z = {0.f, 0.f, 0.f, 0.f};
                f32x4 SA = __builtin_amdgcn_mfma_f32_16x16x32_bf16(kfa0, qf[g][0], z, 0, 0, 0);
                SA = __builtin_amdgcn_mfma_f32_16x16x32_bf16(kfa1, qf[g][1], SA, 0, 0, 0);
                f32x4 SB = __builtin_amdgcn_mfma_f32_16x16x32_bf16(kfb0, qf[g][0], z, 0, 0, 0);
                SB = __builtin_amdgcn_mfma_f32_16x16x32_bf16(kfb1, qf[g][1], SB, 0, 0, 0);

                float p0 = exp2f(SA[0]), p1 = exp2f(SA[1]), p2 = exp2f(SA[2]), p3 = exp2f(SA[3]);
                float p4 = exp2f(SB[0]), p5 = exp2f(SB[1]), p6 = exp2f(SB[2]), p7 = exp2f(SB[3]);
                l_ln[g] += ((p0 + p1) + (p2 + p3)) + ((p4 + p5) + (p6 + p7));
                bf16x8 pb = {(bf16_t)p0, (bf16_t)p1, (bf16_t)p2, (bf16_t)p3,
                             (bf16_t)p4, (bf16_t)p5, (bf16_t)p6, (bf16_t)p7};
                #pragma unroll
                for (int db = 0; db < 4; db++)
                    accO[g][db] = __builtin_amdgcn_mfma_f32_16x16x32_bf16(vf[db], pb, accO[g][db], 0, 0, 0);
            }
        }
    };

    stage(0, 0);

    for (int kt = 0; kt < 16; kt += 2) {
        __builtin_amdgcn_s_barrier();                 // prev reads of buf1 done
        stage(kt + 1, 1);
        __builtin_amdgcn_s_waitcnt(0x0F74);           // vmcnt(4): tile kt resident
        __builtin_amdgcn_s_barrier();
        compute(&Kf[0][0], &Vf[0][0]);
        __builtin_amdgcn_s_barrier();                 // prev reads of buf0 done
        if (kt + 2 < 16) {
            stage(kt + 2, 0);
            __builtin_amdgcn_s_waitcnt(0x0F74);       // vmcnt(4)
        } else {
            __builtin_amdgcn_s_waitcnt(0x0F70);       // vmcnt(0)
        }
        __builtin_amdgcn_s_barrier();
        compute(&Kf[1][0], &Vf[1][0]);
    }

    #pragma unroll
    for (int g = 0; g < 2; g++) {
        float lsum = l_ln[g];
        lsum += __shfl_xor(lsum, 16);
        lsum += __shfl_xor(lsum, 32);
        const int qg = q0 + wid * 32 + g * 16 + ln;
        if (quad == 0) atomicAdd(l_acc + h * 4096 + qg, lsum);
        float* op = out_raw + (size_t)qg * 768 + h * 64 + quad * 4;
        #pragma unroll
        for (int db = 0; db < 4; db++) {
            #pragma unroll
            for (int j = 0; j < 4; j++)
                atomicAdd(op + db * 16 + j, accO[g][db][j]);
        }
    }
}

// ---------------------------------------------------------------------------
// Normalize: out[q, c] = out_raw[q, c] / l[c>>6][q]
// ---------------------------------------------------------------------------
__global__ __launch_bounds__(256) void norm_kernel(const float* __restrict__ out_raw,
                                                   const float* __restrict__ l_acc,
                                                   float* __restrict__ out) {
    const int q = blockIdx.x;
    const int tid = threadIdx.x;
    __shared__ float linv[12];
    if (tid < 12) linv[tid] = 1.0f / l_acc[tid * 4096 + q];
    __syncthreads();
    #pragma unroll
    for (int t = 0; t < 3; t++) {
        int c = tid + t * 256;
        out[(size_t)q * 768 + c] = out_raw[(size_t)q * 768 + c] * linv[c >> 6];
    }
}

// ---------------------------------------------------------------------------
extern "C" void kernel_launch(void* const* d_in, const int* in_sizes, int n_in,
                              void* d_out, int out_size, void* d_ws, size_t ws_size,
                              hipStream_t stream) {
    const float* x      = (const float*)d_in[0];
    const float* proj_w = (const float*)d_in[1];
    const float* proj_b = (const float*)d_in[2];
    const float* ln_g   = (const float*)d_in[3];
    const float* ln_b   = (const float*)d_in[4];
    const float* qkv_w  = (const float*)d_in[5];
    float* out = (float*)d_out;

    char* ws = (char*)d_ws;
    float*  tok_pre = (float*)(ws + 0);              // 12,582,912 B (reused as out_raw)
    bf16_t* tok_b   = (bf16_t*)(ws + 12582912);      //  6,291,456 B
    bf16_t* pw_b    = (bf16_t*)(ws + 18874368);      //    393,216 B (reused as l_acc)
    bf16_t* qw_b    = (bf16_t*)(ws + 19267584);      //  3,538,944 B
    bf16_t* qbuf    = (bf16_t*)(ws + 22806528);      //  6,291,456 B
    bf16_t* kswz    = (bf16_t*)(ws + 29097984);      //  6,291,456 B
    bf16_t* vswz    = (bf16_t*)(ws + 35389440);      //  6,291,456 B (total ~41.7 MB)
    float*  out_raw = tok_pre;                       // free after ln_kernel
    float*  l_acc   = (float*)pw_b;                  // 196,608 B; free after patch_gemm

    cvt_kernel<<<192, 256, 0, stream>>>(proj_w, pw_b, 768 * 256 / 4);
    cvt_kernel<<<1728, 256, 0, stream>>>(qkv_w, qw_b, 2304 * 768 / 4);
    patch_gemm<<<dim3(64, 12), 256, 0, stream>>>(x, pw_b, proj_b, tok_pre);
    ln_kernel<<<4096, 256, 0, stream>>>(tok_pre, ln_g, ln_b, tok_b);
    qkv_gemm<<<dim3(64, 36), 256, 0, stream>>>(tok_b, qw_b, qbuf, kswz, vswz);
    zero_f4<<<3072, 256, 0, stream>>>((float4*)out_raw, 786432);
    zero_f4<<<48, 256, 0, stream>>>((float4*)l_acc, 12288);
    attn_partial<<<dim3(32, 12, 4), 256, 0, stream>>>(qbuf, kswz, vswz, out_raw, l_acc);
    norm_kernel<<<4096, 256, 0, stream>>>(out_raw, l_acc, out);
}

// Round 8
// 245.842 us; speedup vs baseline: 1.3987x; 1.3987x over previous
//
#include <hip/hip_runtime.h>
#include <hip/hip_bf16.h>

typedef __bf16 bf16_t;
typedef __attribute__((ext_vector_type(8))) __bf16 bf16x8;
typedef __attribute__((ext_vector_type(4))) __bf16 bf16x4;
typedef __attribute__((ext_vector_type(4))) float f32x4;

#define QSCALE 0.1803368801111204f  /* 0.125 * log2(e) */

// async global->LDS, 16B per lane; LDS dst = wave-uniform base + lane*16
static __device__ inline void glds16(const bf16_t* g, bf16_t* l) {
    __builtin_amdgcn_global_load_lds(
        (__attribute__((address_space(1))) const void*)g,
        (__attribute__((address_space(3))) void*)l,
        16, 0, 0);
}

// ---------------------------------------------------------------------------
__global__ void cvt_kernel(const float* __restrict__ in, bf16_t* __restrict__ out, int n4) {
    int i = blockIdx.x * 256 + threadIdx.x;
    if (i < n4) {
        float4 v = ((const float4*)in)[i];
        bf16x4 o = {(bf16_t)v.x, (bf16_t)v.y, (bf16_t)v.z, (bf16_t)v.w};
        ((bf16x4*)out)[i] = o;
    }
}

// ---------------------------------------------------------------------------
// Patch-embed GEMM: tok[4096,768] = patches[4096,256] @ proj_w[768,256]^T + b
// ---------------------------------------------------------------------------
__global__ __launch_bounds__(256) void patch_gemm(const float* __restrict__ x,
                                                  const bf16_t* __restrict__ pw,
                                                  const float* __restrict__ pb,
                                                  float* __restrict__ tok) {
    const int bm = blockIdx.x;
    const int bn = blockIdx.y;
    const int tid = threadIdx.x;

    __shared__ bf16_t At[64][264];
    __shared__ bf16_t Bt[64][264];

    #pragma unroll
    for (int t = 0; t < 16; t++) {
        int linear = tid + t * 256;
        int ml = linear >> 6;
        int kv = (linear & 63) << 2;
        int n = bm * 64 + ml;
        int pr = n >> 6, pc = n & 63;
        int i = kv >> 4, j = kv & 15;
        float4 v = *(const float4*)(x + (pr * 16 + i) * 1024 + pc * 16 + j);
        bf16x4 o = {(bf16_t)v.x, (bf16_t)v.y, (bf16_t)v.z, (bf16_t)v.w};
        *(bf16x4*)(&At[ml][kv]) = o;
    }
    #pragma unroll
    for (int t = 0; t < 8; t++) {
        int linear = tid + t * 256;
        int nl = linear >> 5;
        int kv = (linear & 31) << 3;
        *(int4*)(&Bt[nl][kv]) = *(const int4*)(pw + (size_t)(bn * 64 + nl) * 256 + kv);
    }
    __syncthreads();

    const int lane = tid & 63, wid = tid >> 6, ln = lane & 15, quad = lane >> 4;
    f32x4 acc[4];
    #pragma unroll
    for (int s = 0; s < 4; s++) acc[s] = {0.f, 0.f, 0.f, 0.f};

    #pragma unroll
    for (int kk = 0; kk < 8; kk++) {
        bf16x8 af = *(const bf16x8*)(&At[wid * 16 + ln][kk * 32 + quad * 8]);
        #pragma unroll
        for (int s = 0; s < 4; s++) {
            bf16x8 bfr = *(const bf16x8*)(&Bt[s * 16 + ln][kk * 32 + quad * 8]);
            acc[s] = __builtin_amdgcn_mfma_f32_16x16x32_bf16(af, bfr, acc[s], 0, 0, 0);
        }
    }

    #pragma unroll
    for (int s = 0; s < 4; s++) {
        int e = bn * 64 + s * 16 + ln;
        float bias = pb[e];
        #pragma unroll
        for (int r = 0; r < 4; r++) {
            int m = bm * 64 + wid * 16 + quad * 4 + r;
            tok[(size_t)m * 768 + e] = acc[s][r] + bias;
        }
    }
}

// ---------------------------------------------------------------------------
// LayerNorm per token (768), fp32 stats, bf16 out.
// ---------------------------------------------------------------------------
__global__ __launch_bounds__(256) void ln_kernel(const float* __restrict__ tok,
                                                 const float* __restrict__ g,
                                                 const float* __restrict__ b,
                                                 bf16_t* __restrict__ out) {
    const int n = blockIdx.x;
    const int tid = threadIdx.x;
    const float* row = tok + (size_t)n * 768;
    float x0 = row[tid], x1 = row[tid + 256], x2 = row[tid + 512];
    float s = x0 + x1 + x2;
    float s2 = x0 * x0 + x1 * x1 + x2 * x2;
    #pragma unroll
    for (int off = 32; off; off >>= 1) {
        s += __shfl_xor(s, off);
        s2 += __shfl_xor(s2, off);
    }
    __shared__ float ws1[4], ws2[4];
    int wid = tid >> 6;
    if ((tid & 63) == 0) { ws1[wid] = s; ws2[wid] = s2; }
    __syncthreads();
    s = ws1[0] + ws1[1] + ws1[2] + ws1[3];
    s2 = ws2[0] + ws2[1] + ws2[2] + ws2[3];
    float mu = s * (1.f / 768.f);
    float var = s2 * (1.f / 768.f) - mu * mu;
    float r = rsqrtf(var + 1e-6f);
    bf16_t* orow = out + (size_t)n * 768;
    orow[tid]       = (bf16_t)((x0 - mu) * r * g[tid]       + b[tid]);
    orow[tid + 256] = (bf16_t)((x1 - mu) * r * g[tid + 256] + b[tid + 256]);
    orow[tid + 512] = (bf16_t)((x2 - mu) * r * g[tid + 512] + b[tid + 512]);
}

// ---------------------------------------------------------------------------
// QKV GEMM. Epilogue scatter (per 64-key tile blobs, 8 KB each):
//   q -> qb[12][4096][64], pre-scaled by QSCALE
//   k -> kswz: (h,kt64) tile; elem (sb,half,l,j) =
//        K[key=kt*64+sb*16+(l&15)][dim=half*32+(l>>4)*8+j]
//   v -> vswz: (h,kt64) tile; elem ((mm*4+db),l,jp) =
//        V[key=kt*64+(2mm+(jp>>2))*16+(l>>4)*4+(jp&3)][d=db*16+(l&15)]
// ---------------------------------------------------------------------------
__global__ __launch_bounds__(256) void qkv_gemm(const bf16_t* __restrict__ tokb,
                                                const bf16_t* __restrict__ wq,
                                                bf16_t* __restrict__ qb,
                                                bf16_t* __restrict__ kswz,
                                                bf16_t* __restrict__ vswz) {
    const int bm = blockIdx.x;
    const int bn = blockIdx.y;
    const int tid = threadIdx.x;

    __shared__ bf16_t At[64][72];
    __shared__ bf16_t Bt[64][72];

    const int rl = tid >> 3;
    const int c8 = (tid & 7) * 8;
    const int lane = tid & 63, wid = tid >> 6, ln = lane & 15, quad = lane >> 4;

    f32x4 acc[4];
    #pragma unroll
    for (int s = 0; s < 4; s++) acc[s] = {0.f, 0.f, 0.f, 0.f};

    for (int kb0 = 0; kb0 < 768; kb0 += 64) {
        __syncthreads();
        #pragma unroll
        for (int p = 0; p < 2; p++) {
            int row = rl + p * 32;
            *(int4*)(&At[row][c8]) = *(const int4*)(tokb + (size_t)(bm * 64 + row) * 768 + kb0 + c8);
            *(int4*)(&Bt[row][c8]) = *(const int4*)(wq   + (size_t)(bn * 64 + row) * 768 + kb0 + c8);
        }
        __syncthreads();
        #pragma unroll
        for (int kk = 0; kk < 2; kk++) {
            bf16x8 af = *(const bf16x8*)(&At[wid * 16 + ln][kk * 32 + quad * 8]);
            #pragma unroll
            for (int s = 0; s < 4; s++) {
                bf16x8 bfr = *(const bf16x8*)(&Bt[s * 16 + ln][kk * 32 + quad * 8]);
                acc[s] = __builtin_amdgcn_mfma_f32_16x16x32_bf16(af, bfr, acc[s], 0, 0, 0);
            }
        }
    }

    const int ncol0 = bn * 64;
    const int sidx = ncol0 / 768;
    const int head = (ncol0 % 768) >> 6;
    #pragma unroll
    for (int s = 0; s < 4; s++) {
        int dc = s * 16 + ln;
        #pragma unroll
        for (int r = 0; r < 4; r++) {
            int m = bm * 64 + wid * 16 + quad * 4 + r;   // token index = key
            if (sidx == 0) {
                qb[((size_t)(head * 4096 + m)) * 64 + dc] = (bf16_t)(acc[s][r] * QSCALE);
            } else if (sidx == 1) {
                bf16_t val = (bf16_t)acc[s][r];
                int kt = m >> 6, sb = (m >> 4) & 3, lnk = m & 15;
                int half = dc >> 5, quadk = (dc >> 3) & 3, j = dc & 7;
                int l = quadk * 16 + lnk;
                kswz[((size_t)(head * 64 + kt)) * 4096 + sb * 1024 + half * 512 + l * 8 + j] = val;
            } else {
                bf16_t val = (bf16_t)acc[s][r];
                int kt = m >> 6, keyl = m & 63;
                int sblk = keyl >> 4;
                int mm = sblk >> 1, tb = sblk & 1;
                int w16 = keyl & 15, qv = w16 >> 2, jj = w16 & 3;
                int jp = tb * 4 + jj;
                int db = dc >> 4, lnv = dc & 15;
                int l = qv * 16 + lnv;
                vswz[((size_t)(head * 64 + kt)) * 4096 + ((mm * 4 + db) * 64 + l) * 8 + jp] = val;
            }
        }
    }
}

// ---------------------------------------------------------------------------
// Attention v7, split-K=2, NO atomics: block = (128 q-tile, head, chunk of
// 2048 keys). 256 threads = 4 waves x 32 q. 32 x 64-key tiles per chunk,
// async double-buffered via global_load_lds (vmcnt(4) + raw barriers).
// Chunk 0 -> raw0 buffer, chunk 1 -> raw1 (=d_out scratch); l -> l_part.
// Grid: (32, 12, 2).
// ---------------------------------------------------------------------------
__global__ __launch_bounds__(256, 4) void attn_partial(const bf16_t* __restrict__ qbuf,
                                                       const bf16_t* __restrict__ kswz,
                                                       const bf16_t* __restrict__ vswz,
                                                       float* __restrict__ raw0,
                                                       float* __restrict__ raw1,
                                                       float* __restrict__ l_part) {
    const int h = blockIdx.y;
    const int chunk = blockIdx.z;
    const int tid = threadIdx.x;
    const int wid = tid >> 6;           // 0..3
    const int lane = tid & 63;
    const int ln = lane & 15, quad = lane >> 4;
    const int q0 = blockIdx.x * 128;

    __shared__ bf16_t Kf[2][4096];
    __shared__ bf16_t Vf[2][4096];

    // Q B-frags for this wave's two 16-query groups
    bf16x8 qf[2][2];
    #pragma unroll
    for (int g = 0; g < 2; g++) {
        const int q0g = q0 + wid * 32 + g * 16;
        const bf16_t* qrow = qbuf + ((size_t)h * 4096 + q0g + ln) * 64;
        qf[g][0] = *(const bf16x8*)(qrow + quad * 8);
        qf[g][1] = *(const bf16x8*)(qrow + 32 + quad * 8);
    }

    const bf16_t* kg = kswz + (size_t)h * 64 * 4096 + (size_t)chunk * 32 * 4096;
    const bf16_t* vg = vswz + (size_t)h * 64 * 4096 + (size_t)chunk * 32 * 4096;

    f32x4 accO[2][4];
    float l_ln[2] = {0.f, 0.f};
    #pragma unroll
    for (int g = 0; g < 2; g++)
        #pragma unroll
        for (int d = 0; d < 4; d++) accO[g][d] = {0.f, 0.f, 0.f, 0.f};

    // stage one 8KB K + 8KB V tile; 4 waves cover it: 2 K + 2 V glds per wave
    auto stage = [&](int tile, int buf) {
        const bf16_t* kt_g = kg + (size_t)tile * 4096;
        const bf16_t* vt_g = vg + (size_t)tile * 4096;
        #pragma unroll
        for (int i = 0; i < 2; i++) {
            glds16(kt_g + wid * 1024 + i * 512 + lane * 8, &Kf[buf][wid * 1024 + i * 512]);
            glds16(vt_g + wid * 1024 + i * 512 + lane * 8, &Vf[buf][wid * 1024 + i * 512]);
        }
    };

    auto compute = [&](const bf16_t* Kb, const bf16_t* Vb) {
        #pragma unroll
        for (int m = 0; m < 2; m++) {        // m-pair = 32 keys
            bf16x8 vf[4];
            #pragma unroll
            for (int db = 0; db < 4; db++)
                vf[db] = *(const bf16x8*)(Vb + m * 2048 + db * 512 + lane * 8);
            bf16x8 kfa0 = *(const bf16x8*)(Kb + (2 * m) * 1024 + lane * 8);
            bf16x8 kfa1 = *(const bf16x8*)(Kb + (2 * m) * 1024 + 512 + lane * 8);
            bf16x8 kfb0 = *(const bf16x8*)(Kb + (2 * m + 1) * 1024 + lane * 8);
            bf16x8 kfb1 = *(const bf16x8*)(Kb + (2 * m + 1) * 1024 + 512 + lane * 8);
            #pragma unroll
            for (int g = 0; g < 2; g++) {
                f32x4 z = {0.f, 0.f, 0.f, 0.f};
                f32x4 SA = __builtin_amdgcn_mfma_f32_16x16x32_bf16(kfa0, qf[g][0], z, 0, 0, 0);
                SA = __builtin_amdgcn_mfma_f32_16x16x32_bf16(kfa1, qf[g][1], SA, 0, 0, 0);
                f32x4 SB = __builtin_amdgcn_mfma_f32_16x16x32_bf16(kfb0, qf[g][0], z, 0, 0, 0);
                SB = __builtin_amdgcn_mfma_f32_16x16x32_bf16(kfb1, qf[g][1], SB, 0, 0, 0);

                float p0 = exp2f(SA[0]), p1 = exp2f(SA[1]), p2 = exp2f(SA[2]), p3 = exp2f(SA[3]);
                float p4 = exp2f(SB[0]), p5 = exp2f(SB[1]), p6 = exp2f(SB[2]), p7 = exp2f(SB[3]);
                l_ln[g] += ((p0 + p1) + (p2 + p3)) + ((p4 + p5) + (p6 + p7));
                bf16x8 pb = {(bf16_t)p0, (bf16_t)p1, (bf16_t)p2, (bf16_t)p3,
                             (bf16_t)p4, (bf16_t)p5, (bf16_t)p6, (bf16_t)p7};
                #pragma unroll
                for (int db = 0; db < 4; db++)
                    accO[g][db] = __builtin_amdgcn_mfma_f32_16x16x32_bf16(vf[db], pb, accO[g][db], 0, 0, 0);
            }
        }
    };

    stage(0, 0);

    for (int kt = 0; kt < 32; kt += 2) {
        __builtin_amdgcn_s_barrier();                 // prev reads of buf1 done
        stage(kt + 1, 1);
        __builtin_amdgcn_s_waitcnt(0x0F74);           // vmcnt(4): tile kt resident
        __builtin_amdgcn_s_barrier();
        compute(&Kf[0][0], &Vf[0][0]);
        __builtin_amdgcn_s_barrier();                 // prev reads of buf0 done
        if (kt + 2 < 32) {
            stage(kt + 2, 0);
            __builtin_amdgcn_s_waitcnt(0x0F74);       // vmcnt(4)
        } else {
            __builtin_amdgcn_s_waitcnt(0x0F70);       // vmcnt(0)
        }
        __builtin_amdgcn_s_barrier();
        compute(&Kf[1][0], &Vf[1][0]);
    }

    float* base = chunk ? raw1 : raw0;
    #pragma unroll
    for (int g = 0; g < 2; g++) {
        float lsum = l_ln[g];
        lsum += __shfl_xor(lsum, 16);
        lsum += __shfl_xor(lsum, 32);
        const int qg = q0 + wid * 32 + g * 16 + ln;
        if (quad == 0) l_part[(size_t)chunk * 49152 + h * 4096 + qg] = lsum;
        float* op = base + (size_t)qg * 768 + h * 64 + quad * 4;
        #pragma unroll
        for (int db = 0; db < 4; db++)
            *(f32x4*)(op + db * 16) = accO[g][db];
    }
}

// ---------------------------------------------------------------------------
// Normalize + combine: out[q,c] = (raw0[q,c] + raw1[q,c]) / (l0[h][q]+l1[h][q])
// raw1 aliases out (d_out scratch) — element-wise read-then-write, safe.
// ---------------------------------------------------------------------------
__global__ __launch_bounds__(256) void norm_kernel(const float* __restrict__ raw0,
                                                   const float* __restrict__ raw1,
                                                   const float* __restrict__ l_part,
                                                   float* __restrict__ out) {
    const int q = blockIdx.x;
    const int tid = threadIdx.x;
    __shared__ float linv[12];
    if (tid < 12)
        linv[tid] = 1.0f / (l_part[tid * 4096 + q] + l_part[49152 + tid * 4096 + q]);
    __syncthreads();
    #pragma unroll
    for (int t = 0; t < 3; t++) {
        int c = tid + t * 256;
        size_t idx = (size_t)q * 768 + c;
        out[idx] = (raw0[idx] + raw1[idx]) * linv[c >> 6];
    }
}

// ---------------------------------------------------------------------------
extern "C" void kernel_launch(void* const* d_in, const int* in_sizes, int n_in,
                              void* d_out, int out_size, void* d_ws, size_t ws_size,
                              hipStream_t stream) {
    const float* x      = (const float*)d_in[0];
    const float* proj_w = (const float*)d_in[1];
    const float* proj_b = (const float*)d_in[2];
    const float* ln_g   = (const float*)d_in[3];
    const float* ln_b   = (const float*)d_in[4];
    const float* qkv_w  = (const float*)d_in[5];
    float* out = (float*)d_out;

    char* ws = (char*)d_ws;
    float*  tok_pre = (float*)(ws + 0);              // 12,582,912 B (reused: raw0)
    bf16_t* tok_b   = (bf16_t*)(ws + 12582912);      //  6,291,456 B
    bf16_t* pw_b    = (bf16_t*)(ws + 18874368);      //    393,216 B (reused: l_part)
    bf16_t* qw_b    = (bf16_t*)(ws + 19267584);      //  3,538,944 B
    bf16_t* qbuf    = (bf16_t*)(ws + 22806528);      //  6,291,456 B
    bf16_t* kswz    = (bf16_t*)(ws + 29097984);      //  6,291,456 B
    bf16_t* vswz    = (bf16_t*)(ws + 35389440);      //  6,291,456 B (total ~41.7 MB)
    float*  raw0    = tok_pre;                       // dead after ln_kernel
    float*  raw1    = out;                           // d_out used as chunk-1 scratch
    float*  l_part  = (float*)pw_b;                  // dead after patch_gemm

    cvt_kernel<<<192, 256, 0, stream>>>(proj_w, pw_b, 768 * 256 / 4);
    cvt_kernel<<<1728, 256, 0, stream>>>(qkv_w, qw_b, 2304 * 768 / 4);
    patch_gemm<<<dim3(64, 12), 256, 0, stream>>>(x, pw_b, proj_b, tok_pre);
    ln_kernel<<<4096, 256, 0, stream>>>(tok_pre, ln_g, ln_b, tok_b);
    qkv_gemm<<<dim3(64, 36), 256, 0, stream>>>(tok_b, qw_b, qbuf, kswz, vswz);
    attn_partial<<<dim3(32, 12, 2), 256, 0, stream>>>(qbuf, kswz, vswz, raw0, raw1, l_part);
    norm_kernel<<<4096, 256, 0, stream>>>(raw0, raw1, l_part, out);
}

// Round 9
// 224.408 us; speedup vs baseline: 1.5323x; 1.0955x over previous
//
#include <hip/hip_runtime.h>
#include <hip/hip_bf16.h>

typedef __bf16 bf16_t;
typedef __attribute__((ext_vector_type(8))) __bf16 bf16x8;
typedef __attribute__((ext_vector_type(4))) __bf16 bf16x4;
typedef __attribute__((ext_vector_type(4))) float f32x4;

#define QSCALE 0.1803368801111204f  /* 0.125 * log2(e) */

// async global->LDS, 16B per lane; LDS dst = wave-uniform base + lane*16
static __device__ inline void glds16(const bf16_t* g, bf16_t* l) {
    __builtin_amdgcn_global_load_lds(
        (__attribute__((address_space(1))) const void*)g,
        (__attribute__((address_space(3))) void*)l,
        16, 0, 0);
}

// ---------------------------------------------------------------------------
__global__ void cvt_kernel(const float* __restrict__ in, bf16_t* __restrict__ out, int n4) {
    int i = blockIdx.x * 256 + threadIdx.x;
    if (i < n4) {
        float4 v = ((const float4*)in)[i];
        bf16x4 o = {(bf16_t)v.x, (bf16_t)v.y, (bf16_t)v.z, (bf16_t)v.w};
        ((bf16x4*)out)[i] = o;
    }
}

// ---------------------------------------------------------------------------
// Patch-embed GEMM: tok[4096,768] = patches[4096,256] @ proj_w[768,256]^T + b
// ---------------------------------------------------------------------------
__global__ __launch_bounds__(256) void patch_gemm(const float* __restrict__ x,
                                                  const bf16_t* __restrict__ pw,
                                                  const float* __restrict__ pb,
                                                  float* __restrict__ tok) {
    const int bm = blockIdx.x;
    const int bn = blockIdx.y;
    const int tid = threadIdx.x;

    __shared__ bf16_t At[64][264];
    __shared__ bf16_t Bt[64][264];

    #pragma unroll
    for (int t = 0; t < 16; t++) {
        int linear = tid + t * 256;
        int ml = linear >> 6;
        int kv = (linear & 63) << 2;
        int n = bm * 64 + ml;
        int pr = n >> 6, pc = n & 63;
        int i = kv >> 4, j = kv & 15;
        float4 v = *(const float4*)(x + (pr * 16 + i) * 1024 + pc * 16 + j);
        bf16x4 o = {(bf16_t)v.x, (bf16_t)v.y, (bf16_t)v.z, (bf16_t)v.w};
        *(bf16x4*)(&At[ml][kv]) = o;
    }
    #pragma unroll
    for (int t = 0; t < 8; t++) {
        int linear = tid + t * 256;
        int nl = linear >> 5;
        int kv = (linear & 31) << 3;
        *(int4*)(&Bt[nl][kv]) = *(const int4*)(pw + (size_t)(bn * 64 + nl) * 256 + kv);
    }
    __syncthreads();

    const int lane = tid & 63, wid = tid >> 6, ln = lane & 15, quad = lane >> 4;
    f32x4 acc[4];
    #pragma unroll
    for (int s = 0; s < 4; s++) acc[s] = {0.f, 0.f, 0.f, 0.f};

    #pragma unroll
    for (int kk = 0; kk < 8; kk++) {
        bf16x8 af = *(const bf16x8*)(&At[wid * 16 + ln][kk * 32 + quad * 8]);
        #pragma unroll
        for (int s = 0; s < 4; s++) {
            bf16x8 bfr = *(const bf16x8*)(&Bt[s * 16 + ln][kk * 32 + quad * 8]);
            acc[s] = __builtin_amdgcn_mfma_f32_16x16x32_bf16(af, bfr, acc[s], 0, 0, 0);
        }
    }

    #pragma unroll
    for (int s = 0; s < 4; s++) {
        int e = bn * 64 + s * 16 + ln;
        float bias = pb[e];
        #pragma unroll
        for (int r = 0; r < 4; r++) {
            int m = bm * 64 + wid * 16 + quad * 4 + r;
            tok[(size_t)m * 768 + e] = acc[s][r] + bias;
        }
    }
}

// ---------------------------------------------------------------------------
// LayerNorm per token (768), fp32 stats, bf16 out.
// ---------------------------------------------------------------------------
__global__ __launch_bounds__(256) void ln_kernel(const float* __restrict__ tok,
                                                 const float* __restrict__ g,
                                                 const float* __restrict__ b,
                                                 bf16_t* __restrict__ out) {
    const int n = blockIdx.x;
    const int tid = threadIdx.x;
    const float* row = tok + (size_t)n * 768;
    float x0 = row[tid], x1 = row[tid + 256], x2 = row[tid + 512];
    float s = x0 + x1 + x2;
    float s2 = x0 * x0 + x1 * x1 + x2 * x2;
    #pragma unroll
    for (int off = 32; off; off >>= 1) {
        s += __shfl_xor(s, off);
        s2 += __shfl_xor(s2, off);
    }
    __shared__ float ws1[4], ws2[4];
    int wid = tid >> 6;
    if ((tid & 63) == 0) { ws1[wid] = s; ws2[wid] = s2; }
    __syncthreads();
    s = ws1[0] + ws1[1] + ws1[2] + ws1[3];
    s2 = ws2[0] + ws2[1] + ws2[2] + ws2[3];
    float mu = s * (1.f / 768.f);
    float var = s2 * (1.f / 768.f) - mu * mu;
    float r = rsqrtf(var + 1e-6f);
    bf16_t* orow = out + (size_t)n * 768;
    orow[tid]       = (bf16_t)((x0 - mu) * r * g[tid]       + b[tid]);
    orow[tid + 256] = (bf16_t)((x1 - mu) * r * g[tid + 256] + b[tid + 256]);
    orow[tid + 512] = (bf16_t)((x2 - mu) * r * g[tid + 512] + b[tid + 512]);
}

// ---------------------------------------------------------------------------
// QKV GEMM. Epilogue scatter (per 64-key tile blobs, 8 KB each):
//   q -> qb[12][4096][64], pre-scaled by QSCALE
//   k -> kswz: (h,kt64) tile; elem (sb,half,l,j) =
//        K[key=kt*64+sb*16+(l&15)][dim=half*32+(l>>4)*8+j]
//   v -> vswz: (h,kt64) tile; elem ((mm*4+db),l,jp) =
//        V[key=kt*64+(2mm+(jp>>2))*16+(l>>4)*4+(jp&3)][d=db*16+(l&15)]
// ---------------------------------------------------------------------------
__global__ __launch_bounds__(256) void qkv_gemm(const bf16_t* __restrict__ tokb,
                                                const bf16_t* __restrict__ wq,
                                                bf16_t* __restrict__ qb,
                                                bf16_t* __restrict__ kswz,
                                                bf16_t* __restrict__ vswz) {
    const int bm = blockIdx.x;
    const int bn = blockIdx.y;
    const int tid = threadIdx.x;

    __shared__ bf16_t At[64][72];
    __shared__ bf16_t Bt[64][72];

    const int rl = tid >> 3;
    const int c8 = (tid & 7) * 8;
    const int lane = tid & 63, wid = tid >> 6, ln = lane & 15, quad = lane >> 4;

    f32x4 acc[4];
    #pragma unroll
    for (int s = 0; s < 4; s++) acc[s] = {0.f, 0.f, 0.f, 0.f};

    for (int kb0 = 0; kb0 < 768; kb0 += 64) {
        __syncthreads();
        #pragma unroll
        for (int p = 0; p < 2; p++) {
            int row = rl + p * 32;
            *(int4*)(&At[row][c8]) = *(const int4*)(tokb + (size_t)(bm * 64 + row) * 768 + kb0 + c8);
            *(int4*)(&Bt[row][c8]) = *(const int4*)(wq   + (size_t)(bn * 64 + row) * 768 + kb0 + c8);
        }
        __syncthreads();
        #pragma unroll
        for (int kk = 0; kk < 2; kk++) {
            bf16x8 af = *(const bf16x8*)(&At[wid * 16 + ln][kk * 32 + quad * 8]);
            #pragma unroll
            for (int s = 0; s < 4; s++) {
                bf16x8 bfr = *(const bf16x8*)(&Bt[s * 16 + ln][kk * 32 + quad * 8]);
                acc[s] = __builtin_amdgcn_mfma_f32_16x16x32_bf16(af, bfr, acc[s], 0, 0, 0);
            }
        }
    }

    const int ncol0 = bn * 64;
    const int sidx = ncol0 / 768;
    const int head = (ncol0 % 768) >> 6;
    #pragma unroll
    for (int s = 0; s < 4; s++) {
        int dc = s * 16 + ln;
        #pragma unroll
        for (int r = 0; r < 4; r++) {
            int m = bm * 64 + wid * 16 + quad * 4 + r;   // token index = key
            if (sidx == 0) {
                qb[((size_t)(head * 4096 + m)) * 64 + dc] = (bf16_t)(acc[s][r] * QSCALE);
            } else if (sidx == 1) {
                bf16_t val = (bf16_t)acc[s][r];
                int kt = m >> 6, sb = (m >> 4) & 3, lnk = m & 15;
                int half = dc >> 5, quadk = (dc >> 3) & 3, j = dc & 7;
                int l = quadk * 16 + lnk;
                kswz[((size_t)(head * 64 + kt)) * 4096 + sb * 1024 + half * 512 + l * 8 + j] = val;
            } else {
                bf16_t val = (bf16_t)acc[s][r];
                int kt = m >> 6, keyl = m & 63;
                int sblk = keyl >> 4;
                int mm = sblk >> 1, tb = sblk & 1;
                int w16 = keyl & 15, qv = w16 >> 2, jj = w16 & 3;
                int jp = tb * 4 + jj;
                int db = dc >> 4, lnv = dc & 15;
                int l = qv * 16 + lnv;
                vswz[((size_t)(head * 64 + kt)) * 4096 + ((mm * 4 + db) * 64 + l) * 8 + jp] = val;
            }
        }
    }
}

// ---------------------------------------------------------------------------
// Attention v8 = v7 with launch_bounds(256,2): VGPR cap 256 (not 64) -> no
// scratch spill. Split-K=2, no atomics, async double-buffered glds pipeline.
// Grid: (32, 12, 2), 256 threads = 4 waves x 32 q.
// ---------------------------------------------------------------------------
__global__ __launch_bounds__(256, 2) void attn_partial(const bf16_t* __restrict__ qbuf,
                                                       const bf16_t* __restrict__ kswz,
                                                       const bf16_t* __restrict__ vswz,
                                                       float* __restrict__ raw0,
                                                       float* __restrict__ raw1,
                                                       float* __restrict__ l_part) {
    const int h = blockIdx.y;
    const int chunk = blockIdx.z;
    const int tid = threadIdx.x;
    const int wid = tid >> 6;           // 0..3
    const int lane = tid & 63;
    const int ln = lane & 15, quad = lane >> 4;
    const int q0 = blockIdx.x * 128;

    __shared__ bf16_t Kf[2][4096];
    __shared__ bf16_t Vf[2][4096];

    // Q B-frags for this wave's two 16-query groups
    bf16x8 qf[2][2];
    #pragma unroll
    for (int g = 0; g < 2; g++) {
        const int q0g = q0 + wid * 32 + g * 16;
        const bf16_t* qrow = qbuf + ((size_t)h * 4096 + q0g + ln) * 64;
        qf[g][0] = *(const bf16x8*)(qrow + quad * 8);
        qf[g][1] = *(const bf16x8*)(qrow + 32 + quad * 8);
    }

    const bf16_t* kg = kswz + (size_t)h * 64 * 4096 + (size_t)chunk * 32 * 4096;
    const bf16_t* vg = vswz + (size_t)h * 64 * 4096 + (size_t)chunk * 32 * 4096;

    f32x4 accO[2][4];
    float l_ln[2] = {0.f, 0.f};
    #pragma unroll
    for (int g = 0; g < 2; g++)
        #pragma unroll
        for (int d = 0; d < 4; d++) accO[g][d] = {0.f, 0.f, 0.f, 0.f};

    // stage one 8KB K + 8KB V tile; 4 waves cover it: 2 K + 2 V glds per wave
    auto stage = [&](int tile, int buf) {
        const bf16_t* kt_g = kg + (size_t)tile * 4096;
        const bf16_t* vt_g = vg + (size_t)tile * 4096;
        #pragma unroll
        for (int i = 0; i < 2; i++) {
            glds16(kt_g + wid * 1024 + i * 512 + lane * 8, &Kf[buf][wid * 1024 + i * 512]);
            glds16(vt_g + wid * 1024 + i * 512 + lane * 8, &Vf[buf][wid * 1024 + i * 512]);
        }
    };

    auto compute = [&](const bf16_t* Kb, const bf16_t* Vb) {
        #pragma unroll
        for (int m = 0; m < 2; m++) {        // m-pair = 32 keys
            bf16x8 vf[4];
            #pragma unroll
            for (int db = 0; db < 4; db++)
                vf[db] = *(const bf16x8*)(Vb + m * 2048 + db * 512 + lane * 8);
            bf16x8 kfa0 = *(const bf16x8*)(Kb + (2 * m) * 1024 + lane * 8);
            bf16x8 kfa1 = *(const bf16x8*)(Kb + (2 * m) * 1024 + 512 + lane * 8);
            bf16x8 kfb0 = *(const bf16x8*)(Kb + (2 * m + 1) * 1024 + lane * 8);
            bf16x8 kfb1 = *(const bf16x8*)(Kb + (2 * m + 1) * 1024 + 512 + lane * 8);
            #pragma unroll
            for (int g = 0; g < 2; g++) {
                f32x4 z = {0.f, 0.f, 0.f, 0.f};
                f32x4 SA = __builtin_amdgcn_mfma_f32_16x16x32_bf16(kfa0, qf[g][0], z, 0, 0, 0);
                SA = __builtin_amdgcn_mfma_f32_16x16x32_bf16(kfa1, qf[g][1], SA, 0, 0, 0);
                f32x4 SB = __builtin_amdgcn_mfma_f32_16x16x32_bf16(kfb0, qf[g][0], z, 0, 0, 0);
                SB = __builtin_amdgcn_mfma_f32_16x16x32_bf16(kfb1, qf[g][1], SB, 0, 0, 0);

                float p0 = exp2f(SA[0]), p1 = exp2f(SA[1]), p2 = exp2f(SA[2]), p3 = exp2f(SA[3]);
                float p4 = exp2f(SB[0]), p5 = exp2f(SB[1]), p6 = exp2f(SB[2]), p7 = exp2f(SB[3]);
                l_ln[g] += ((p0 + p1) + (p2 + p3)) + ((p4 + p5) + (p6 + p7));
                bf16x8 pb = {(bf16_t)p0, (bf16_t)p1, (bf16_t)p2, (bf16_t)p3,
                             (bf16_t)p4, (bf16_t)p5, (bf16_t)p6, (bf16_t)p7};
                #pragma unroll
                for (int db = 0; db < 4; db++)
                    accO[g][db] = __builtin_amdgcn_mfma_f32_16x16x32_bf16(vf[db], pb, accO[g][db], 0, 0, 0);
            }
        }
    };

    stage(0, 0);

    for (int kt = 0; kt < 32; kt += 2) {
        __builtin_amdgcn_s_barrier();                 // prev reads of buf1 done
        stage(kt + 1, 1);
        __builtin_amdgcn_s_waitcnt(0x0F74);           // vmcnt(4): tile kt resident
        __builtin_amdgcn_s_barrier();
        compute(&Kf[0][0], &Vf[0][0]);
        __builtin_amdgcn_s_barrier();                 // prev reads of buf0 done
        if (kt + 2 < 32) {
            stage(kt + 2, 0);
            __builtin_amdgcn_s_waitcnt(0x0F74);       // vmcnt(4)
        } else {
            __builtin_amdgcn_s_waitcnt(0x0F70);       // vmcnt(0)
        }
        __builtin_amdgcn_s_barrier();
        compute(&Kf[1][0], &Vf[1][0]);
    }

    float* base = chunk ? raw1 : raw0;
    #pragma unroll
    for (int g = 0; g < 2; g++) {
        float lsum = l_ln[g];
        lsum += __shfl_xor(lsum, 16);
        lsum += __shfl_xor(lsum, 32);
        const int qg = q0 + wid * 32 + g * 16 + ln;
        if (quad == 0) l_part[(size_t)chunk * 49152 + h * 4096 + qg] = lsum;
        float* op = base + (size_t)qg * 768 + h * 64 + quad * 4;
        #pragma unroll
        for (int db = 0; db < 4; db++)
            *(f32x4*)(op + db * 16) = accO[g][db];
    }
}

// ---------------------------------------------------------------------------
// Normalize + combine: out[q,c] = (raw0[q,c] + raw1[q,c]) / (l0[h][q]+l1[h][q])
// raw1 aliases out (d_out scratch) — element-wise read-then-write, safe.
// ---------------------------------------------------------------------------
__global__ __launch_bounds__(256) void norm_kernel(const float* __restrict__ raw0,
                                                   const float* __restrict__ raw1,
                                                   const float* __restrict__ l_part,
                                                   float* __restrict__ out) {
    const int q = blockIdx.x;
    const int tid = threadIdx.x;
    __shared__ float linv[12];
    if (tid < 12)
        linv[tid] = 1.0f / (l_part[tid * 4096 + q] + l_part[49152 + tid * 4096 + q]);
    __syncthreads();
    #pragma unroll
    for (int t = 0; t < 3; t++) {
        int c = tid + t * 256;
        size_t idx = (size_t)q * 768 + c;
        out[idx] = (raw0[idx] + raw1[idx]) * linv[c >> 6];
    }
}

// ---------------------------------------------------------------------------
extern "C" void kernel_launch(void* const* d_in, const int* in_sizes, int n_in,
                              void* d_out, int out_size, void* d_ws, size_t ws_size,
                              hipStream_t stream) {
    const float* x      = (const float*)d_in[0];
    const float* proj_w = (const float*)d_in[1];
    const float* proj_b = (const float*)d_in[2];
    const float* ln_g   = (const float*)d_in[3];
    const float* ln_b   = (const float*)d_in[4];
    const float* qkv_w  = (const float*)d_in[5];
    float* out = (float*)d_out;

    char* ws = (char*)d_ws;
    float*  tok_pre = (float*)(ws + 0);              // 12,582,912 B (reused: raw0)
    bf16_t* tok_b   = (bf16_t*)(ws + 12582912);      //  6,291,456 B
    bf16_t* pw_b    = (bf16_t*)(ws + 18874368);      //    393,216 B (reused: l_part)
    bf16_t* qw_b    = (bf16_t*)(ws + 19267584);      //  3,538,944 B
    bf16_t* qbuf    = (bf16_t*)(ws + 22806528);      //  6,291,456 B
    bf16_t* kswz    = (bf16_t*)(ws + 29097984);      //  6,291,456 B
    bf16_t* vswz    = (bf16_t*)(ws + 35389440);      //  6,291,456 B (total ~41.7 MB)
    float*  raw0    = tok_pre;                       // dead after ln_kernel
    float*  raw1    = out;                           // d_out used as chunk-1 scratch
    float*  l_part  = (float*)pw_b;                  // dead after patch_gemm

    cvt_kernel<<<192, 256, 0, stream>>>(proj_w, pw_b, 768 * 256 / 4);
    cvt_kernel<<<1728, 256, 0, stream>>>(qkv_w, qw_b, 2304 * 768 / 4);
    patch_gemm<<<dim3(64, 12), 256, 0, stream>>>(x, pw_b, proj_b, tok_pre);
    ln_kernel<<<4096, 256, 0, stream>>>(tok_pre, ln_g, ln_b, tok_b);
    qkv_gemm<<<dim3(64, 36), 256, 0, stream>>>(tok_b, qw_b, qbuf, kswz, vswz);
    attn_partial<<<dim3(32, 12, 2), 256, 0, stream>>>(qbuf, kswz, vswz, raw0, raw1, l_part);
    norm_kernel<<<4096, 256, 0, stream>>>(raw0, raw1, l_part, out);
}

// Round 10
// 213.043 us; speedup vs baseline: 1.6140x; 1.0533x over previous
//
#include <hip/hip_runtime.h>
#include <hip/hip_bf16.h>

typedef __bf16 bf16_t;
typedef __attribute__((ext_vector_type(8))) __bf16 bf16x8;
typedef __attribute__((ext_vector_type(4))) __bf16 bf16x4;
typedef __attribute__((ext_vector_type(4))) float f32x4;
typedef __attribute__((ext_vector_type(4))) unsigned int uint4v;

#define QSCALE 0.1803368801111204f  /* 0.125 * log2(e) */

// async global->LDS, 16B per lane; LDS dst = wave-uniform base + lane*16
static __device__ inline void glds16(const bf16_t* g, bf16_t* l) {
    __builtin_amdgcn_global_load_lds(
        (__attribute__((address_space(1))) const void*)g,
        (__attribute__((address_space(3))) void*)l,
        16, 0, 0);
}

// pack two fp32 -> bf16x2 by truncation (top 16 bits), single v_perm_b32
static __device__ inline unsigned int pack_trunc(float lo, float hi) {
    return __builtin_amdgcn_perm(__builtin_bit_cast(unsigned int, hi),
                                 __builtin_bit_cast(unsigned int, lo),
                                 0x07060302u);
}

// ---------------------------------------------------------------------------
__global__ void cvt_kernel(const float* __restrict__ in, bf16_t* __restrict__ out, int n4) {
    int i = blockIdx.x * 256 + threadIdx.x;
    if (i < n4) {
        float4 v = ((const float4*)in)[i];
        bf16x4 o = {(bf16_t)v.x, (bf16_t)v.y, (bf16_t)v.z, (bf16_t)v.w};
        ((bf16x4*)out)[i] = o;
    }
}

// ---------------------------------------------------------------------------
// Patch-embed GEMM: tok[4096,768] = patches[4096,256] @ proj_w[768,256]^T + b
// ---------------------------------------------------------------------------
__global__ __launch_bounds__(256) void patch_gemm(const float* __restrict__ x,
                                                  const bf16_t* __restrict__ pw,
                                                  const float* __restrict__ pb,
                                                  float* __restrict__ tok) {
    const int bm = blockIdx.x;
    const int bn = blockIdx.y;
    const int tid = threadIdx.x;

    __shared__ bf16_t At[64][264];
    __shared__ bf16_t Bt[64][264];

    #pragma unroll
    for (int t = 0; t < 16; t++) {
        int linear = tid + t * 256;
        int ml = linear >> 6;
        int kv = (linear & 63) << 2;
        int n = bm * 64 + ml;
        int pr = n >> 6, pc = n & 63;
        int i = kv >> 4, j = kv & 15;
        float4 v = *(const float4*)(x + (pr * 16 + i) * 1024 + pc * 16 + j);
        bf16x4 o = {(bf16_t)v.x, (bf16_t)v.y, (bf16_t)v.z, (bf16_t)v.w};
        *(bf16x4*)(&At[ml][kv]) = o;
    }
    #pragma unroll
    for (int t = 0; t < 8; t++) {
        int linear = tid + t * 256;
        int nl = linear >> 5;
        int kv = (linear & 31) << 3;
        *(int4*)(&Bt[nl][kv]) = *(const int4*)(pw + (size_t)(bn * 64 + nl) * 256 + kv);
    }
    __syncthreads();

    const int lane = tid & 63, wid = tid >> 6, ln = lane & 15, quad = lane >> 4;
    f32x4 acc[4];
    #pragma unroll
    for (int s = 0; s < 4; s++) acc[s] = {0.f, 0.f, 0.f, 0.f};

    #pragma unroll
    for (int kk = 0; kk < 8; kk++) {
        bf16x8 af = *(const bf16x8*)(&At[wid * 16 + ln][kk * 32 + quad * 8]);
        #pragma unroll
        for (int s = 0; s < 4; s++) {
            bf16x8 bfr = *(const bf16x8*)(&Bt[s * 16 + ln][kk * 32 + quad * 8]);
            acc[s] = __builtin_amdgcn_mfma_f32_16x16x32_bf16(af, bfr, acc[s], 0, 0, 0);
        }
    }

    #pragma unroll
    for (int s = 0; s < 4; s++) {
        int e = bn * 64 + s * 16 + ln;
        float bias = pb[e];
        #pragma unroll
        for (int r = 0; r < 4; r++) {
            int m = bm * 64 + wid * 16 + quad * 4 + r;
            tok[(size_t)m * 768 + e] = acc[s][r] + bias;
        }
    }
}

// ---------------------------------------------------------------------------
// LayerNorm per token (768), fp32 stats, bf16 out.
// ---------------------------------------------------------------------------
__global__ __launch_bounds__(256) void ln_kernel(const float* __restrict__ tok,
                                                 const float* __restrict__ g,
                                                 const float* __restrict__ b,
                                                 bf16_t* __restrict__ out) {
    const int n = blockIdx.x;
    const int tid = threadIdx.x;
    const float* row = tok + (size_t)n * 768;
    float x0 = row[tid], x1 = row[tid + 256], x2 = row[tid + 512];
    float s = x0 + x1 + x2;
    float s2 = x0 * x0 + x1 * x1 + x2 * x2;
    #pragma unroll
    for (int off = 32; off; off >>= 1) {
        s += __shfl_xor(s, off);
        s2 += __shfl_xor(s2, off);
    }
    __shared__ float ws1[4], ws2[4];
    int wid = tid >> 6;
    if ((tid & 63) == 0) { ws1[wid] = s; ws2[wid] = s2; }
    __syncthreads();
    s = ws1[0] + ws1[1] + ws1[2] + ws1[3];
    s2 = ws2[0] + ws2[1] + ws2[2] + ws2[3];
    float mu = s * (1.f / 768.f);
    float var = s2 * (1.f / 768.f) - mu * mu;
    float r = rsqrtf(var + 1e-6f);
    bf16_t* orow = out + (size_t)n * 768;
    orow[tid]       = (bf16_t)((x0 - mu) * r * g[tid]       + b[tid]);
    orow[tid + 256] = (bf16_t)((x1 - mu) * r * g[tid + 256] + b[tid + 256]);
    orow[tid + 512] = (bf16_t)((x2 - mu) * r * g[tid + 512] + b[tid + 512]);
}

// ---------------------------------------------------------------------------
// QKV GEMM. Epilogue scatter (per 64-key tile blobs, 8 KB each):
//   q -> qb[12][4096][64], pre-scaled by QSCALE
//   k -> kswz: (h,kt64) tile; elem (sb,half,l,j) =
//        K[key=kt*64+sb*16+(l&15)][dim=half*32+(l>>4)*8+j]
//   v -> vswz: (h,kt64) tile; elem ((mm*4+db),l,jp) =
//        V[key=kt*64+(2mm+(jp>>2))*16+(l>>4)*4+(jp&3)][d=db*16+(l&15)]
// ---------------------------------------------------------------------------
__global__ __launch_bounds__(256) void qkv_gemm(const bf16_t* __restrict__ tokb,
                                                const bf16_t* __restrict__ wq,
                                                bf16_t* __restrict__ qb,
                                                bf16_t* __restrict__ kswz,
                                                bf16_t* __restrict__ vswz) {
    const int bm = blockIdx.x;
    const int bn = blockIdx.y;
    const int tid = threadIdx.x;

    __shared__ bf16_t At[64][72];
    __shared__ bf16_t Bt[64][72];

    const int rl = tid >> 3;
    const int c8 = (tid & 7) * 8;
    const int lane = tid & 63, wid = tid >> 6, ln = lane & 15, quad = lane >> 4;

    f32x4 acc[4];
    #pragma unroll
    for (int s = 0; s < 4; s++) acc[s] = {0.f, 0.f, 0.f, 0.f};

    for (int kb0 = 0; kb0 < 768; kb0 += 64) {
        __syncthreads();
        #pragma unroll
        for (int p = 0; p < 2; p++) {
            int row = rl + p * 32;
            *(int4*)(&At[row][c8]) = *(const int4*)(tokb + (size_t)(bm * 64 + row) * 768 + kb0 + c8);
            *(int4*)(&Bt[row][c8]) = *(const int4*)(wq   + (size_t)(bn * 64 + row) * 768 + kb0 + c8);
        }
        __syncthreads();
        #pragma unroll
        for (int kk = 0; kk < 2; kk++) {
            bf16x8 af = *(const bf16x8*)(&At[wid * 16 + ln][kk * 32 + quad * 8]);
            #pragma unroll
            for (int s = 0; s < 4; s++) {
                bf16x8 bfr = *(const bf16x8*)(&Bt[s * 16 + ln][kk * 32 + quad * 8]);
                acc[s] = __builtin_amdgcn_mfma_f32_16x16x32_bf16(af, bfr, acc[s], 0, 0, 0);
            }
        }
    }

    const int ncol0 = bn * 64;
    const int sidx = ncol0 / 768;
    const int head = (ncol0 % 768) >> 6;
    #pragma unroll
    for (int s = 0; s < 4; s++) {
        int dc = s * 16 + ln;
        #pragma unroll
        for (int r = 0; r < 4; r++) {
            int m = bm * 64 + wid * 16 + quad * 4 + r;   // token index = key
            if (sidx == 0) {
                qb[((size_t)(head * 4096 + m)) * 64 + dc] = (bf16_t)(acc[s][r] * QSCALE);
            } else if (sidx == 1) {
                bf16_t val = (bf16_t)acc[s][r];
                int kt = m >> 6, sb = (m >> 4) & 3, lnk = m & 15;
                int half = dc >> 5, quadk = (dc >> 3) & 3, j = dc & 7;
                int l = quadk * 16 + lnk;
                kswz[((size_t)(head * 64 + kt)) * 4096 + sb * 1024 + half * 512 + l * 8 + j] = val;
            } else {
                bf16_t val = (bf16_t)acc[s][r];
                int kt = m >> 6, keyl = m & 63;
                int sblk = keyl >> 4;
                int mm = sblk >> 1, tb = sblk & 1;
                int w16 = keyl & 15, qv = w16 >> 2, jj = w16 & 3;
                int jp = tb * 4 + jj;
                int db = dc >> 4, lnv = dc & 15;
                int l = qv * 16 + lnv;
                vswz[((size_t)(head * 64 + kt)) * 4096 + ((mm * 4 + db) * 64 + l) * 8 + jp] = val;
            }
        }
    }
}

// ---------------------------------------------------------------------------
// Attention v9: split-K=2, no atomics, async dbuf glds pipeline; softmax
// epilogue VALU-minimized: perm-truncated bf16 pack + l via ones-MFMA on the
// same truncated P (consistent quantization; no shuffle reduction).
// Grid: (32, 12, 2), 256 threads = 4 waves x 32 q.
// ---------------------------------------------------------------------------
__global__ __launch_bounds__(256, 2) void attn_partial(const bf16_t* __restrict__ qbuf,
                                                       const bf16_t* __restrict__ kswz,
                                                       const bf16_t* __restrict__ vswz,
                                                       float* __restrict__ raw0,
                                                       float* __restrict__ raw1,
                                                       float* __restrict__ l_part) {
    const int h = blockIdx.y;
    const int chunk = blockIdx.z;
    const int tid = threadIdx.x;
    const int wid = tid >> 6;           // 0..3
    const int lane = tid & 63;
    const int ln = lane & 15, quad = lane >> 4;
    const int q0 = blockIdx.x * 128;

    __shared__ bf16_t Kf[2][4096];
    __shared__ bf16_t Vf[2][4096];

    // Q B-frags for this wave's two 16-query groups
    bf16x8 qf[2][2];
    #pragma unroll
    for (int g = 0; g < 2; g++) {
        const int q0g = q0 + wid * 32 + g * 16;
        const bf16_t* qrow = qbuf + ((size_t)h * 4096 + q0g + ln) * 64;
        qf[g][0] = *(const bf16x8*)(qrow + quad * 8);
        qf[g][1] = *(const bf16x8*)(qrow + 32 + quad * 8);
    }

    // all-ones A fragment for the l row-sum MFMA
    bf16x8 ones;
    #pragma unroll
    for (int i = 0; i < 8; i++) ones[i] = (bf16_t)1.0f;

    const bf16_t* kg = kswz + (size_t)h * 64 * 4096 + (size_t)chunk * 32 * 4096;
    const bf16_t* vg = vswz + (size_t)h * 64 * 4096 + (size_t)chunk * 32 * 4096;

    f32x4 accO[2][4];
    f32x4 accL[2];
    #pragma unroll
    for (int g = 0; g < 2; g++) {
        accL[g] = {0.f, 0.f, 0.f, 0.f};
        #pragma unroll
        for (int d = 0; d < 4; d++) accO[g][d] = {0.f, 0.f, 0.f, 0.f};
    }

    // stage one 8KB K + 8KB V tile; 4 waves cover it: 2 K + 2 V glds per wave
    auto stage = [&](int tile, int buf) {
        const bf16_t* kt_g = kg + (size_t)tile * 4096;
        const bf16_t* vt_g = vg + (size_t)tile * 4096;
        #pragma unroll
        for (int i = 0; i < 2; i++) {
            glds16(kt_g + wid * 1024 + i * 512 + lane * 8, &Kf[buf][wid * 1024 + i * 512]);
            glds16(vt_g + wid * 1024 + i * 512 + lane * 8, &Vf[buf][wid * 1024 + i * 512]);
        }
    };

    auto compute = [&](const bf16_t* Kb, const bf16_t* Vb) {
        #pragma unroll
        for (int m = 0; m < 2; m++) {        // m-pair = 32 keys
            bf16x8 vf[4];
            #pragma unroll
            for (int db = 0; db < 4; db++)
                vf[db] = *(const bf16x8*)(Vb + m * 2048 + db * 512 + lane * 8);
            bf16x8 kfa0 = *(const bf16x8*)(Kb + (2 * m) * 1024 + lane * 8);
            bf16x8 kfa1 = *(const bf16x8*)(Kb + (2 * m) * 1024 + 512 + lane * 8);
            bf16x8 kfb0 = *(const bf16x8*)(Kb + (2 * m + 1) * 1024 + lane * 8);
            bf16x8 kfb1 = *(const bf16x8*)(Kb + (2 * m + 1) * 1024 + 512 + lane * 8);
            #pragma unroll
            for (int g = 0; g < 2; g++) {
                f32x4 z = {0.f, 0.f, 0.f, 0.f};
                f32x4 SA = __builtin_amdgcn_mfma_f32_16x16x32_bf16(kfa0, qf[g][0], z, 0, 0, 0);
                SA = __builtin_amdgcn_mfma_f32_16x16x32_bf16(kfa1, qf[g][1], SA, 0, 0, 0);
                f32x4 SB = __builtin_amdgcn_mfma_f32_16x16x32_bf16(kfb0, qf[g][0], z, 0, 0, 0);
                SB = __builtin_amdgcn_mfma_f32_16x16x32_bf16(kfb1, qf[g][1], SB, 0, 0, 0);

                float e0 = exp2f(SA[0]), e1 = exp2f(SA[1]), e2 = exp2f(SA[2]), e3 = exp2f(SA[3]);
                float e4 = exp2f(SB[0]), e5 = exp2f(SB[1]), e6 = exp2f(SB[2]), e7 = exp2f(SB[3]);
                uint4v u = {pack_trunc(e0, e1), pack_trunc(e2, e3),
                            pack_trunc(e4, e5), pack_trunc(e6, e7)};
                bf16x8 pb = __builtin_bit_cast(bf16x8, u);
                accL[g] = __builtin_amdgcn_mfma_f32_16x16x32_bf16(ones, pb, accL[g], 0, 0, 0);
                #pragma unroll
                for (int db = 0; db < 4; db++)
                    accO[g][db] = __builtin_amdgcn_mfma_f32_16x16x32_bf16(vf[db], pb, accO[g][db], 0, 0, 0);
            }
        }
    };

    stage(0, 0);

    for (int kt = 0; kt < 32; kt += 2) {
        __builtin_amdgcn_s_barrier();                 // prev reads of buf1 done
        stage(kt + 1, 1);
        __builtin_amdgcn_s_waitcnt(0x0F74);           // vmcnt(4): tile kt resident
        __builtin_amdgcn_s_barrier();
        compute(&Kf[0][0], &Vf[0][0]);
        __builtin_amdgcn_s_barrier();                 // prev reads of buf0 done
        if (kt + 2 < 32) {
            stage(kt + 2, 0);
            __builtin_amdgcn_s_waitcnt(0x0F74);       // vmcnt(4)
        } else {
            __builtin_amdgcn_s_waitcnt(0x0F70);       // vmcnt(0)
        }
        __builtin_amdgcn_s_barrier();
        compute(&Kf[1][0], &Vf[1][0]);
    }

    float* base = chunk ? raw1 : raw0;
    #pragma unroll
    for (int g = 0; g < 2; g++) {
        // every lane's accL[g][0] holds l[q=ln] (rows identical for ones-A)
        const int qg = q0 + wid * 32 + g * 16 + ln;
        if (quad == 0) l_part[(size_t)chunk * 49152 + h * 4096 + qg] = accL[g][0];
        float* op = base + (size_t)qg * 768 + h * 64 + quad * 4;
        #pragma unroll
        for (int db = 0; db < 4; db++)
            *(f32x4*)(op + db * 16) = accO[g][db];
    }
}

// ---------------------------------------------------------------------------
// Normalize + combine: out[q,c] = (raw0[q,c] + raw1[q,c]) / (l0[h][q]+l1[h][q])
// raw1 aliases out (d_out scratch) — element-wise read-then-write, safe.
// ---------------------------------------------------------------------------
__global__ __launch_bounds__(256) void norm_kernel(const float* __restrict__ raw0,
                                                   const float* __restrict__ raw1,
                                                   const float* __restrict__ l_part,
                                                   float* __restrict__ out) {
    const int q = blockIdx.x;
    const int tid = threadIdx.x;
    __shared__ float linv[12];
    if (tid < 12)
        linv[tid] = 1.0f / (l_part[tid * 4096 + q] + l_part[49152 + tid * 4096 + q]);
    __syncthreads();
    #pragma unroll
    for (int t = 0; t < 3; t++) {
        int c = tid + t * 256;
        size_t idx = (size_t)q * 768 + c;
        out[idx] = (raw0[idx] + raw1[idx]) * linv[c >> 6];
    }
}

// ---------------------------------------------------------------------------
extern "C" void kernel_launch(void* const* d_in, const int* in_sizes, int n_in,
                              void* d_out, int out_size, void* d_ws, size_t ws_size,
                              hipStream_t stream) {
    const float* x      = (const float*)d_in[0];
    const float* proj_w = (const float*)d_in[1];
    const float* proj_b = (const float*)d_in[2];
    const float* ln_g   = (const float*)d_in[3];
    const float* ln_b   = (const float*)d_in[4];
    const float* qkv_w  = (const float*)d_in[5];
    float* out = (float*)d_out;

    char* ws = (char*)d_ws;
    float*  tok_pre = (float*)(ws + 0);              // 12,582,912 B (reused: raw0)
    bf16_t* tok_b   = (bf16_t*)(ws + 12582912);      //  6,291,456 B
    bf16_t* pw_b    = (bf16_t*)(ws + 18874368);      //    393,216 B (reused: l_part)
    bf16_t* qw_b    = (bf16_t*)(ws + 19267584);      //  3,538,944 B
    bf16_t* qbuf    = (bf16_t*)(ws + 22806528);      //  6,291,456 B
    bf16_t* kswz    = (bf16_t*)(ws + 29097984);      //  6,291,456 B
    bf16_t* vswz    = (bf16_t*)(ws + 35389440);      //  6,291,456 B (total ~41.7 MB)
    float*  raw0    = tok_pre;                       // dead after ln_kernel
    float*  raw1    = out;                           // d_out used as chunk-1 scratch
    float*  l_part  = (float*)pw_b;                  // dead after patch_gemm

    cvt_kernel<<<192, 256, 0, stream>>>(proj_w, pw_b, 768 * 256 / 4);
    cvt_kernel<<<1728, 256, 0, stream>>>(qkv_w, qw_b, 2304 * 768 / 4);
    patch_gemm<<<dim3(64, 12), 256, 0, stream>>>(x, pw_b, proj_b, tok_pre);
    ln_kernel<<<4096, 256, 0, stream>>>(tok_pre, ln_g, ln_b, tok_b);
    qkv_gemm<<<dim3(64, 36), 256, 0, stream>>>(tok_b, qw_b, qbuf, kswz, vswz);
    attn_partial<<<dim3(32, 12, 2), 256, 0, stream>>>(qbuf, kswz, vswz, raw0, raw1, l_part);
    norm_kernel<<<4096, 256, 0, stream>>>(raw0, raw1, l_part, out);
}

// Round 11
// 192.706 us; speedup vs baseline: 1.7844x; 1.1055x over previous
//
#include <hip/hip_runtime.h>
#include <hip/hip_bf16.h>

typedef __bf16 bf16_t;
typedef __attribute__((ext_vector_type(8))) __bf16 bf16x8;
typedef __attribute__((ext_vector_type(4))) __bf16 bf16x4;
typedef __attribute__((ext_vector_type(4))) float f32x4;
typedef __attribute__((ext_vector_type(4))) unsigned int uint4v;

#define QSCALE 0.1803368801111204f  /* 0.125 * log2(e) */

// async global->LDS, 16B per lane; LDS dst = wave-uniform base + lane*16
static __device__ inline void glds16(const bf16_t* g, bf16_t* l) {
    __builtin_amdgcn_global_load_lds(
        (__attribute__((address_space(1))) const void*)g,
        (__attribute__((address_space(3))) void*)l,
        16, 0, 0);
}

// raw hardware v_exp_f32 (input bounded — no libm range/denorm fixup needed)
static __device__ inline float hwexp2(float x) {
#if __has_builtin(__builtin_amdgcn_exp2f)
    return __builtin_amdgcn_exp2f(x);
#else
    float r;
    asm("v_exp_f32 %0, %1" : "=v"(r) : "v"(x));
    return r;
#endif
}

// pack two fp32 -> bf16x2 by truncation (top 16 bits), single v_perm_b32
static __device__ inline unsigned int pack_trunc(float lo, float hi) {
    return __builtin_amdgcn_perm(__builtin_bit_cast(unsigned int, hi),
                                 __builtin_bit_cast(unsigned int, lo),
                                 0x07060302u);
}

// ---------------------------------------------------------------------------
__global__ void cvt_kernel(const float* __restrict__ in, bf16_t* __restrict__ out, int n4) {
    int i = blockIdx.x * 256 + threadIdx.x;
    if (i < n4) {
        float4 v = ((const float4*)in)[i];
        bf16x4 o = {(bf16_t)v.x, (bf16_t)v.y, (bf16_t)v.z, (bf16_t)v.w};
        ((bf16x4*)out)[i] = o;
    }
}

// ---------------------------------------------------------------------------
// Patch-embed GEMM: tok[4096,768] = patches[4096,256] @ proj_w[768,256]^T + b
// ---------------------------------------------------------------------------
__global__ __launch_bounds__(256) void patch_gemm(const float* __restrict__ x,
                                                  const bf16_t* __restrict__ pw,
                                                  const float* __restrict__ pb,
                                                  float* __restrict__ tok) {
    const int bm = blockIdx.x;
    const int bn = blockIdx.y;
    const int tid = threadIdx.x;

    __shared__ bf16_t At[64][264];
    __shared__ bf16_t Bt[64][264];

    #pragma unroll
    for (int t = 0; t < 16; t++) {
        int linear = tid + t * 256;
        int ml = linear >> 6;
        int kv = (linear & 63) << 2;
        int n = bm * 64 + ml;
        int pr = n >> 6, pc = n & 63;
        int i = kv >> 4, j = kv & 15;
        float4 v = *(const float4*)(x + (pr * 16 + i) * 1024 + pc * 16 + j);
        bf16x4 o = {(bf16_t)v.x, (bf16_t)v.y, (bf16_t)v.z, (bf16_t)v.w};
        *(bf16x4*)(&At[ml][kv]) = o;
    }
    #pragma unroll
    for (int t = 0; t < 8; t++) {
        int linear = tid + t * 256;
        int nl = linear >> 5;
        int kv = (linear & 31) << 3;
        *(int4*)(&Bt[nl][kv]) = *(const int4*)(pw + (size_t)(bn * 64 + nl) * 256 + kv);
    }
    __syncthreads();

    const int lane = tid & 63, wid = tid >> 6, ln = lane & 15, quad = lane >> 4;
    f32x4 acc[4];
    #pragma unroll
    for (int s = 0; s < 4; s++) acc[s] = {0.f, 0.f, 0.f, 0.f};

    #pragma unroll
    for (int kk = 0; kk < 8; kk++) {
        bf16x8 af = *(const bf16x8*)(&At[wid * 16 + ln][kk * 32 + quad * 8]);
        #pragma unroll
        for (int s = 0; s < 4; s++) {
            bf16x8 bfr = *(const bf16x8*)(&Bt[s * 16 + ln][kk * 32 + quad * 8]);
            acc[s] = __builtin_amdgcn_mfma_f32_16x16x32_bf16(af, bfr, acc[s], 0, 0, 0);
        }
    }

    #pragma unroll
    for (int s = 0; s < 4; s++) {
        int e = bn * 64 + s * 16 + ln;
        float bias = pb[e];
        #pragma unroll
        for (int r = 0; r < 4; r++) {
            int m = bm * 64 + wid * 16 + quad * 4 + r;
            tok[(size_t)m * 768 + e] = acc[s][r] + bias;
        }
    }
}

// ---------------------------------------------------------------------------
// LayerNorm per token (768), fp32 stats, bf16 out.
// ---------------------------------------------------------------------------
__global__ __launch_bounds__(256) void ln_kernel(const float* __restrict__ tok,
                                                 const float* __restrict__ g,
                                                 const float* __restrict__ b,
                                                 bf16_t* __restrict__ out) {
    const int n = blockIdx.x;
    const int tid = threadIdx.x;
    const float* row = tok + (size_t)n * 768;
    float x0 = row[tid], x1 = row[tid + 256], x2 = row[tid + 512];
    float s = x0 + x1 + x2;
    float s2 = x0 * x0 + x1 * x1 + x2 * x2;
    #pragma unroll
    for (int off = 32; off; off >>= 1) {
        s += __shfl_xor(s, off);
        s2 += __shfl_xor(s2, off);
    }
    __shared__ float ws1[4], ws2[4];
    int wid = tid >> 6;
    if ((tid & 63) == 0) { ws1[wid] = s; ws2[wid] = s2; }
    __syncthreads();
    s = ws1[0] + ws1[1] + ws1[2] + ws1[3];
    s2 = ws2[0] + ws2[1] + ws2[2] + ws2[3];
    float mu = s * (1.f / 768.f);
    float var = s2 * (1.f / 768.f) - mu * mu;
    float r = rsqrtf(var + 1e-6f);
    bf16_t* orow = out + (size_t)n * 768;
    orow[tid]       = (bf16_t)((x0 - mu) * r * g[tid]       + b[tid]);
    orow[tid + 256] = (bf16_t)((x1 - mu) * r * g[tid + 256] + b[tid + 256]);
    orow[tid + 512] = (bf16_t)((x2 - mu) * r * g[tid + 512] + b[tid + 512]);
}

// ---------------------------------------------------------------------------
// QKV GEMM. Epilogue scatter (per 64-key tile blobs, 8 KB each):
//   q -> qb[12][4096][64], pre-scaled by QSCALE
//   k -> kswz: (h,kt64) tile; elem (sb,half,l,j) =
//        K[key=kt*64+sb*16+(l&15)][dim=half*32+(l>>4)*8+j]
//   v -> vswz: (h,kt64) tile; elem ((mm*4+db),l,jp) =
//        V[key=kt*64+(2mm+(jp>>2))*16+(l>>4)*4+(jp&3)][d=db*16+(l&15)]
// ---------------------------------------------------------------------------
__global__ __launch_bounds__(256) void qkv_gemm(const bf16_t* __restrict__ tokb,
                                                const bf16_t* __restrict__ wq,
                                                bf16_t* __restrict__ qb,
                                                bf16_t* __restrict__ kswz,
                                                bf16_t* __restrict__ vswz) {
    const int bm = blockIdx.x;
    const int bn = blockIdx.y;
    const int tid = threadIdx.x;

    __shared__ bf16_t At[64][72];
    __shared__ bf16_t Bt[64][72];

    const int rl = tid >> 3;
    const int c8 = (tid & 7) * 8;
    const int lane = tid & 63, wid = tid >> 6, ln = lane & 15, quad = lane >> 4;

    f32x4 acc[4];
    #pragma unroll
    for (int s = 0; s < 4; s++) acc[s] = {0.f, 0.f, 0.f, 0.f};

    for (int kb0 = 0; kb0 < 768; kb0 += 64) {
        __syncthreads();
        #pragma unroll
        for (int p = 0; p < 2; p++) {
            int row = rl + p * 32;
            *(int4*)(&At[row][c8]) = *(const int4*)(tokb + (size_t)(bm * 64 + row) * 768 + kb0 + c8);
            *(int4*)(&Bt[row][c8]) = *(const int4*)(wq   + (size_t)(bn * 64 + row) * 768 + kb0 + c8);
        }
        __syncthreads();
        #pragma unroll
        for (int kk = 0; kk < 2; kk++) {
            bf16x8 af = *(const bf16x8*)(&At[wid * 16 + ln][kk * 32 + quad * 8]);
            #pragma unroll
            for (int s = 0; s < 4; s++) {
                bf16x8 bfr = *(const bf16x8*)(&Bt[s * 16 + ln][kk * 32 + quad * 8]);
                acc[s] = __builtin_amdgcn_mfma_f32_16x16x32_bf16(af, bfr, acc[s], 0, 0, 0);
            }
        }
    }

    const int ncol0 = bn * 64;
    const int sidx = ncol0 / 768;
    const int head = (ncol0 % 768) >> 6;
    #pragma unroll
    for (int s = 0; s < 4; s++) {
        int dc = s * 16 + ln;
        #pragma unroll
        for (int r = 0; r < 4; r++) {
            int m = bm * 64 + wid * 16 + quad * 4 + r;   // token index = key
            if (sidx == 0) {
                qb[((size_t)(head * 4096 + m)) * 64 + dc] = (bf16_t)(acc[s][r] * QSCALE);
            } else if (sidx == 1) {
                bf16_t val = (bf16_t)acc[s][r];
                int kt = m >> 6, sb = (m >> 4) & 3, lnk = m & 15;
                int half = dc >> 5, quadk = (dc >> 3) & 3, j = dc & 7;
                int l = quadk * 16 + lnk;
                kswz[((size_t)(head * 64 + kt)) * 4096 + sb * 1024 + half * 512 + l * 8 + j] = val;
            } else {
                bf16_t val = (bf16_t)acc[s][r];
                int kt = m >> 6, keyl = m & 63;
                int sblk = keyl >> 4;
                int mm = sblk >> 1, tb = sblk & 1;
                int w16 = keyl & 15, qv = w16 >> 2, jj = w16 & 3;
                int jp = tb * 4 + jj;
                int db = dc >> 4, lnv = dc & 15;
                int l = qv * 16 + lnv;
                vswz[((size_t)(head * 64 + kt)) * 4096 + ((mm * 4 + db) * 64 + l) * 8 + jp] = val;
            }
        }
    }
}

// ---------------------------------------------------------------------------
// Attention v10 = v9 with raw v_exp_f32 (hwexp2) instead of libm exp2f.
// Split-K=2, no atomics, async dbuf glds pipeline, perm-truncated P pack,
// l via ones-MFMA. Grid: (32, 12, 2), 256 threads = 4 waves x 32 q.
// ---------------------------------------------------------------------------
__global__ __launch_bounds__(256, 2) void attn_partial(const bf16_t* __restrict__ qbuf,
                                                       const bf16_t* __restrict__ kswz,
                                                       const bf16_t* __restrict__ vswz,
                                                       float* __restrict__ raw0,
                                                       float* __restrict__ raw1,
                                                       float* __restrict__ l_part) {
    const int h = blockIdx.y;
    const int chunk = blockIdx.z;
    const int tid = threadIdx.x;
    const int wid = tid >> 6;           // 0..3
    const int lane = tid & 63;
    const int ln = lane & 15, quad = lane >> 4;
    const int q0 = blockIdx.x * 128;

    __shared__ bf16_t Kf[2][4096];
    __shared__ bf16_t Vf[2][4096];

    // Q B-frags for this wave's two 16-query groups
    bf16x8 qf[2][2];
    #pragma unroll
    for (int g = 0; g < 2; g++) {
        const int q0g = q0 + wid * 32 + g * 16;
        const bf16_t* qrow = qbuf + ((size_t)h * 4096 + q0g + ln) * 64;
        qf[g][0] = *(const bf16x8*)(qrow + quad * 8);
        qf[g][1] = *(const bf16x8*)(qrow + 32 + quad * 8);
    }

    // all-ones A fragment for the l row-sum MFMA
    bf16x8 ones;
    #pragma unroll
    for (int i = 0; i < 8; i++) ones[i] = (bf16_t)1.0f;

    const bf16_t* kg = kswz + (size_t)h * 64 * 4096 + (size_t)chunk * 32 * 4096;
    const bf16_t* vg = vswz + (size_t)h * 64 * 4096 + (size_t)chunk * 32 * 4096;

    f32x4 accO[2][4];
    f32x4 accL[2];
    #pragma unroll
    for (int g = 0; g < 2; g++) {
        accL[g] = {0.f, 0.f, 0.f, 0.f};
        #pragma unroll
        for (int d = 0; d < 4; d++) accO[g][d] = {0.f, 0.f, 0.f, 0.f};
    }

    // stage one 8KB K + 8KB V tile; 4 waves cover it: 2 K + 2 V glds per wave
    auto stage = [&](int tile, int buf) {
        const bf16_t* kt_g = kg + (size_t)tile * 4096;
        const bf16_t* vt_g = vg + (size_t)tile * 4096;
        #pragma unroll
        for (int i = 0; i < 2; i++) {
            glds16(kt_g + wid * 1024 + i * 512 + lane * 8, &Kf[buf][wid * 1024 + i * 512]);
            glds16(vt_g + wid * 1024 + i * 512 + lane * 8, &Vf[buf][wid * 1024 + i * 512]);
        }
    };

    auto compute = [&](const bf16_t* Kb, const bf16_t* Vb) {
        #pragma unroll
        for (int m = 0; m < 2; m++) {        // m-pair = 32 keys
            bf16x8 vf[4];
            #pragma unroll
            for (int db = 0; db < 4; db++)
                vf[db] = *(const bf16x8*)(Vb + m * 2048 + db * 512 + lane * 8);
            bf16x8 kfa0 = *(const bf16x8*)(Kb + (2 * m) * 1024 + lane * 8);
            bf16x8 kfa1 = *(const bf16x8*)(Kb + (2 * m) * 1024 + 512 + lane * 8);
            bf16x8 kfb0 = *(const bf16x8*)(Kb + (2 * m + 1) * 1024 + lane * 8);
            bf16x8 kfb1 = *(const bf16x8*)(Kb + (2 * m + 1) * 1024 + 512 + lane * 8);
            #pragma unroll
            for (int g = 0; g < 2; g++) {
                f32x4 z = {0.f, 0.f, 0.f, 0.f};
                f32x4 SA = __builtin_amdgcn_mfma_f32_16x16x32_bf16(kfa0, qf[g][0], z, 0, 0, 0);
                SA = __builtin_amdgcn_mfma_f32_16x16x32_bf16(kfa1, qf[g][1], SA, 0, 0, 0);
                f32x4 SB = __builtin_amdgcn_mfma_f32_16x16x32_bf16(kfb0, qf[g][0], z, 0, 0, 0);
                SB = __builtin_amdgcn_mfma_f32_16x16x32_bf16(kfb1, qf[g][1], SB, 0, 0, 0);

                float e0 = hwexp2(SA[0]), e1 = hwexp2(SA[1]), e2 = hwexp2(SA[2]), e3 = hwexp2(SA[3]);
                float e4 = hwexp2(SB[0]), e5 = hwexp2(SB[1]), e6 = hwexp2(SB[2]), e7 = hwexp2(SB[3]);
                uint4v u = {pack_trunc(e0, e1), pack_trunc(e2, e3),
                            pack_trunc(e4, e5), pack_trunc(e6, e7)};
                bf16x8 pb = __builtin_bit_cast(bf16x8, u);
                accL[g] = __builtin_amdgcn_mfma_f32_16x16x32_bf16(ones, pb, accL[g], 0, 0, 0);
                #pragma unroll
                for (int db = 0; db < 4; db++)
                    accO[g][db] = __builtin_amdgcn_mfma_f32_16x16x32_bf16(vf[db], pb, accO[g][db], 0, 0, 0);
            }
        }
    };

    stage(0, 0);

    for (int kt = 0; kt < 32; kt += 2) {
        __builtin_amdgcn_s_barrier();                 // prev reads of buf1 done
        stage(kt + 1, 1);
        __builtin_amdgcn_s_waitcnt(0x0F74);           // vmcnt(4): tile kt resident
        __builtin_amdgcn_s_barrier();
        compute(&Kf[0][0], &Vf[0][0]);
        __builtin_amdgcn_s_barrier();                 // prev reads of buf0 done
        if (kt + 2 < 32) {
            stage(kt + 2, 0);
            __builtin_amdgcn_s_waitcnt(0x0F74);       // vmcnt(4)
        } else {
            __builtin_amdgcn_s_waitcnt(0x0F70);       // vmcnt(0)
        }
        __builtin_amdgcn_s_barrier();
        compute(&Kf[1][0], &Vf[1][0]);
    }

    float* base = chunk ? raw1 : raw0;
    #pragma unroll
    for (int g = 0; g < 2; g++) {
        // every lane's accL[g][0] holds l[q=ln] (rows identical for ones-A)
        const int qg = q0 + wid * 32 + g * 16 + ln;
        if (quad == 0) l_part[(size_t)chunk * 49152 + h * 4096 + qg] = accL[g][0];
        float* op = base + (size_t)qg * 768 + h * 64 + quad * 4;
        #pragma unroll
        for (int db = 0; db < 4; db++)
            *(f32x4*)(op + db * 16) = accO[g][db];
    }
}

// ---------------------------------------------------------------------------
// Normalize + combine: out[q,c] = (raw0[q,c] + raw1[q,c]) / (l0[h][q]+l1[h][q])
// raw1 aliases out (d_out scratch) — element-wise read-then-write, safe.
// ---------------------------------------------------------------------------
__global__ __launch_bounds__(256) void norm_kernel(const float* __restrict__ raw0,
                                                   const float* __restrict__ raw1,
                                                   const float* __restrict__ l_part,
                                                   float* __restrict__ out) {
    const int q = blockIdx.x;
    const int tid = threadIdx.x;
    __shared__ float linv[12];
    if (tid < 12)
        linv[tid] = 1.0f / (l_part[tid * 4096 + q] + l_part[49152 + tid * 4096 + q]);
    __syncthreads();
    #pragma unroll
    for (int t = 0; t < 3; t++) {
        int c = tid + t * 256;
        size_t idx = (size_t)q * 768 + c;
        out[idx] = (raw0[idx] + raw1[idx]) * linv[c >> 6];
    }
}

// ---------------------------------------------------------------------------
extern "C" void kernel_launch(void* const* d_in, const int* in_sizes, int n_in,
                              void* d_out, int out_size, void* d_ws, size_t ws_size,
                              hipStream_t stream) {
    const float* x      = (const float*)d_in[0];
    const float* proj_w = (const float*)d_in[1];
    const float* proj_b = (const float*)d_in[2];
    const float* ln_g   = (const float*)d_in[3];
    const float* ln_b   = (const float*)d_in[4];
    const float* qkv_w  = (const float*)d_in[5];
    float* out = (float*)d_out;

    char* ws = (char*)d_ws;
    float*  tok_pre = (float*)(ws + 0);              // 12,582,912 B (reused: raw0)
    bf16_t* tok_b   = (bf16_t*)(ws + 12582912);      //  6,291,456 B
    bf16_t* pw_b    = (bf16_t*)(ws + 18874368);      //    393,216 B (reused: l_part)
    bf16_t* qw_b    = (bf16_t*)(ws + 19267584);      //  3,538,944 B
    bf16_t* qbuf    = (bf16_t*)(ws + 22806528);      //  6,291,456 B
    bf16_t* kswz    = (bf16_t*)(ws + 29097984);      //  6,291,456 B
    bf16_t* vswz    = (bf16_t*)(ws + 35389440);      //  6,291,456 B (total ~41.7 MB)
    float*  raw0    = tok_pre;                       // dead after ln_kernel
    float*  raw1    = out;                           // d_out used as chunk-1 scratch
    float*  l_part  = (float*)pw_b;                  // dead after patch_gemm

    cvt_kernel<<<192, 256, 0, stream>>>(proj_w, pw_b, 768 * 256 / 4);
    cvt_kernel<<<1728, 256, 0, stream>>>(qkv_w, qw_b, 2304 * 768 / 4);
    patch_gemm<<<dim3(64, 12), 256, 0, stream>>>(x, pw_b, proj_b, tok_pre);
    ln_kernel<<<4096, 256, 0, stream>>>(tok_pre, ln_g, ln_b, tok_b);
    qkv_gemm<<<dim3(64, 36), 256, 0, stream>>>(tok_b, qw_b, qbuf, kswz, vswz);
    attn_partial<<<dim3(32, 12, 2), 256, 0, stream>>>(qbuf, kswz, vswz, raw0, raw1, l_part);
    norm_kernel<<<4096, 256, 0, stream>>>(raw0, raw1, l_part, out);
}

// Round 12
// 189.070 us; speedup vs baseline: 1.8187x; 1.0192x over previous
//
#include <hip/hip_runtime.h>
#include <hip/hip_bf16.h>

typedef __bf16 bf16_t;
typedef __attribute__((ext_vector_type(8))) __bf16 bf16x8;
typedef __attribute__((ext_vector_type(4))) __bf16 bf16x4;
typedef __attribute__((ext_vector_type(4))) float f32x4;
typedef __attribute__((ext_vector_type(4))) unsigned int uint4v;

#define QSCALE 0.1803368801111204f  /* 0.125 * log2(e) */

// async global->LDS, 16B per lane; LDS dst = wave-uniform base + lane*16
static __device__ inline void glds16(const bf16_t* g, bf16_t* l) {
    __builtin_amdgcn_global_load_lds(
        (__attribute__((address_space(1))) const void*)g,
        (__attribute__((address_space(3))) void*)l,
        16, 0, 0);
}

// raw hardware v_exp_f32 (input bounded — no libm range/denorm fixup needed)
static __device__ inline float hwexp2(float x) {
#if __has_builtin(__builtin_amdgcn_exp2f)
    return __builtin_amdgcn_exp2f(x);
#else
    float r;
    asm("v_exp_f32 %0, %1" : "=v"(r) : "v"(x));
    return r;
#endif
}

// pack two fp32 -> bf16x2 by truncation (top 16 bits), single v_perm_b32
static __device__ inline unsigned int pack_trunc(float lo, float hi) {
    return __builtin_amdgcn_perm(__builtin_bit_cast(unsigned int, hi),
                                 __builtin_bit_cast(unsigned int, lo),
                                 0x07060302u);
}

// ---------------------------------------------------------------------------
// fused fp32 -> bf16 convert for both weight tensors (one launch)
// ---------------------------------------------------------------------------
__global__ void cvt2_kernel(const float* __restrict__ a, bf16_t* __restrict__ oa, int na4,
                            const float* __restrict__ b, bf16_t* __restrict__ ob, int nb4) {
    int i = blockIdx.x * 256 + threadIdx.x;
    if (i < na4) {
        float4 v = ((const float4*)a)[i];
        bf16x4 o = {(bf16_t)v.x, (bf16_t)v.y, (bf16_t)v.z, (bf16_t)v.w};
        ((bf16x4*)oa)[i] = o;
    } else {
        int j = i - na4;
        if (j < nb4) {
            float4 v = ((const float4*)b)[j];
            bf16x4 o = {(bf16_t)v.x, (bf16_t)v.y, (bf16_t)v.z, (bf16_t)v.w};
            ((bf16x4*)ob)[j] = o;
        }
    }
}

// ---------------------------------------------------------------------------
// Patch-embed GEMM: tok[4096,768] = patches[4096,256] @ proj_w[768,256]^T + b
// ---------------------------------------------------------------------------
__global__ __launch_bounds__(256) void patch_gemm(const float* __restrict__ x,
                                                  const bf16_t* __restrict__ pw,
                                                  const float* __restrict__ pb,
                                                  float* __restrict__ tok) {
    const int bm = blockIdx.x;
    const int bn = blockIdx.y;
    const int tid = threadIdx.x;

    __shared__ bf16_t At[64][264];
    __shared__ bf16_t Bt[64][264];

    #pragma unroll
    for (int t = 0; t < 16; t++) {
        int linear = tid + t * 256;
        int ml = linear >> 6;
        int kv = (linear & 63) << 2;
        int n = bm * 64 + ml;
        int pr = n >> 6, pc = n & 63;
        int i = kv >> 4, j = kv & 15;
        float4 v = *(const float4*)(x + (pr * 16 + i) * 1024 + pc * 16 + j);
        bf16x4 o = {(bf16_t)v.x, (bf16_t)v.y, (bf16_t)v.z, (bf16_t)v.w};
        *(bf16x4*)(&At[ml][kv]) = o;
    }
    #pragma unroll
    for (int t = 0; t < 8; t++) {
        int linear = tid + t * 256;
        int nl = linear >> 5;
        int kv = (linear & 31) << 3;
        *(int4*)(&Bt[nl][kv]) = *(const int4*)(pw + (size_t)(bn * 64 + nl) * 256 + kv);
    }
    __syncthreads();

    const int lane = tid & 63, wid = tid >> 6, ln = lane & 15, quad = lane >> 4;
    f32x4 acc[4];
    #pragma unroll
    for (int s = 0; s < 4; s++) acc[s] = {0.f, 0.f, 0.f, 0.f};

    #pragma unroll
    for (int kk = 0; kk < 8; kk++) {
        bf16x8 af = *(const bf16x8*)(&At[wid * 16 + ln][kk * 32 + quad * 8]);
        #pragma unroll
        for (int s = 0; s < 4; s++) {
            bf16x8 bfr = *(const bf16x8*)(&Bt[s * 16 + ln][kk * 32 + quad * 8]);
            acc[s] = __builtin_amdgcn_mfma_f32_16x16x32_bf16(af, bfr, acc[s], 0, 0, 0);
        }
    }

    #pragma unroll
    for (int s = 0; s < 4; s++) {
        int e = bn * 64 + s * 16 + ln;
        float bias = pb[e];
        #pragma unroll
        for (int r = 0; r < 4; r++) {
            int m = bm * 64 + wid * 16 + quad * 4 + r;
            tok[(size_t)m * 768 + e] = acc[s][r] + bias;
        }
    }
}

// ---------------------------------------------------------------------------
// LayerNorm per token (768), fp32 stats, bf16 out.
// ---------------------------------------------------------------------------
__global__ __launch_bounds__(256) void ln_kernel(const float* __restrict__ tok,
                                                 const float* __restrict__ g,
                                                 const float* __restrict__ b,
                                                 bf16_t* __restrict__ out) {
    const int n = blockIdx.x;
    const int tid = threadIdx.x;
    const float* row = tok + (size_t)n * 768;
    float x0 = row[tid], x1 = row[tid + 256], x2 = row[tid + 512];
    float s = x0 + x1 + x2;
    float s2 = x0 * x0 + x1 * x1 + x2 * x2;
    #pragma unroll
    for (int off = 32; off; off >>= 1) {
        s += __shfl_xor(s, off);
        s2 += __shfl_xor(s2, off);
    }
    __shared__ float ws1[4], ws2[4];
    int wid = tid >> 6;
    if ((tid & 63) == 0) { ws1[wid] = s; ws2[wid] = s2; }
    __syncthreads();
    s = ws1[0] + ws1[1] + ws1[2] + ws1[3];
    s2 = ws2[0] + ws2[1] + ws2[2] + ws2[3];
    float mu = s * (1.f / 768.f);
    float var = s2 * (1.f / 768.f) - mu * mu;
    float r = rsqrtf(var + 1e-6f);
    bf16_t* orow = out + (size_t)n * 768;
    orow[tid]       = (bf16_t)((x0 - mu) * r * g[tid]       + b[tid]);
    orow[tid + 256] = (bf16_t)((x1 - mu) * r * g[tid + 256] + b[tid + 256]);
    orow[tid + 512] = (bf16_t)((x2 - mu) * r * g[tid + 512] + b[tid + 512]);
}

// ---------------------------------------------------------------------------
// QKV GEMM v2 — m97 structure: 128x128 tile, BK=64, glds16 staging, 4 waves
// in 2x2, 4x4 f32x4 acc per wave. Epilogue scatters q/k/v (same swizzles):
//   q -> qb[12][4096][64] (pre-scaled); k -> kswz tiles; v -> vswz tiles.
// Grid: (32, 18), 256 threads. bn 0..5 = q, 6..11 = k, 12..17 = v.
// ---------------------------------------------------------------------------
__global__ __launch_bounds__(256) void qkv_gemm(const bf16_t* __restrict__ tokb,
                                                const bf16_t* __restrict__ wq,
                                                bf16_t* __restrict__ qb,
                                                bf16_t* __restrict__ kswz,
                                                bf16_t* __restrict__ vswz) {
    const int bm = blockIdx.x;   // 32 m-tiles (128 tokens)
    const int bn = blockIdx.y;   // 18 n-tiles (128 cols)
    const int tid = threadIdx.x;
    const int wid = tid >> 6, lane = tid & 63;
    const int ln = lane & 15, quad = lane >> 4;
    const int wm = wid & 1, wn = wid >> 1;   // wave 2x2

    __shared__ bf16_t At[128 * 64];
    __shared__ bf16_t Bt[128 * 64];

    f32x4 acc[4][4];
    #pragma unroll
    for (int sm = 0; sm < 4; sm++)
        #pragma unroll
        for (int sn = 0; sn < 4; sn++) acc[sm][sn] = {0.f, 0.f, 0.f, 0.f};

    const int srow = wid * 32 + (lane >> 3);  // +8i
    const int scol = (lane & 7) * 8;

    for (int kb0 = 0; kb0 < 768; kb0 += 64) {
        __syncthreads();
        #pragma unroll
        for (int i = 0; i < 4; i++) {
            glds16(tokb + (size_t)(bm * 128 + srow + i * 8) * 768 + kb0 + scol,
                   At + wid * 2048 + i * 512);
            glds16(wq + (size_t)(bn * 128 + srow + i * 8) * 768 + kb0 + scol,
                   Bt + wid * 2048 + i * 512);
        }
        __syncthreads();   // compiler drains vmcnt before barrier
        #pragma unroll
        for (int kk = 0; kk < 2; kk++) {
            bf16x8 af[4], bfr[4];
            #pragma unroll
            for (int s = 0; s < 4; s++) {
                af[s]  = *(const bf16x8*)(At + (wm * 64 + s * 16 + ln) * 64 + kk * 32 + quad * 8);
                bfr[s] = *(const bf16x8*)(Bt + (wn * 64 + s * 16 + ln) * 64 + kk * 32 + quad * 8);
            }
            #pragma unroll
            for (int sm = 0; sm < 4; sm++)
                #pragma unroll
                for (int sn = 0; sn < 4; sn++)
                    acc[sm][sn] = __builtin_amdgcn_mfma_f32_16x16x32_bf16(af[sm], bfr[sn], acc[sm][sn], 0, 0, 0);
        }
    }

    const int sidx = bn / 6;                       // 0=q 1=k 2=v (block-uniform)
    const int head = (bn % 6) * 2 + wn;            // wave-uniform
    #pragma unroll
    for (int sn = 0; sn < 4; sn++) {
        int dc = sn * 16 + ln;                     // 0..63 within head
        #pragma unroll
        for (int sm = 0; sm < 4; sm++) {
            #pragma unroll
            for (int r = 0; r < 4; r++) {
                int m = bm * 128 + wm * 64 + sm * 16 + quad * 4 + r;   // token = key
                float v = acc[sm][sn][r];
                if (sidx == 0) {
                    qb[((size_t)(head * 4096 + m)) * 64 + dc] = (bf16_t)(v * QSCALE);
                } else if (sidx == 1) {
                    bf16_t val = (bf16_t)v;
                    int kt = m >> 6, sb = (m >> 4) & 3, lnk = m & 15;
                    int half = dc >> 5, quadk = (dc >> 3) & 3, j = dc & 7;
                    int l = quadk * 16 + lnk;
                    kswz[((size_t)(head * 64 + kt)) * 4096 + sb * 1024 + half * 512 + l * 8 + j] = val;
                } else {
                    bf16_t val = (bf16_t)v;
                    int kt = m >> 6, keyl = m & 63;
                    int sblk = keyl >> 4;
                    int mm = sblk >> 1, tb = sblk & 1;
                    int w16 = keyl & 15, qv = w16 >> 2, jj = w16 & 3;
                    int jp = tb * 4 + jj;
                    int db = dc >> 4, lnv = dc & 15;
                    int l = qv * 16 + lnv;
                    vswz[((size_t)(head * 64 + kt)) * 4096 + ((mm * 4 + db) * 64 + l) * 8 + jp] = val;
                }
            }
        }
    }
}

// ---------------------------------------------------------------------------
// Attention: split-K=2, no atomics, async dbuf glds pipeline, raw v_exp_f32,
// perm-truncated P pack, l via ones-MFMA.
// Grid: (32, 12, 2), 256 threads = 4 waves x 32 q.
// ---------------------------------------------------------------------------
__global__ __launch_bounds__(256, 2) void attn_partial(const bf16_t* __restrict__ qbuf,
                                                       const bf16_t* __restrict__ kswz,
                                                       const bf16_t* __restrict__ vswz,
                                                       float* __restrict__ raw0,
                                                       float* __restrict__ raw1,
                                                       float* __restrict__ l_part) {
    const int h = blockIdx.y;
    const int chunk = blockIdx.z;
    const int tid = threadIdx.x;
    const int wid = tid >> 6;           // 0..3
    const int lane = tid & 63;
    const int ln = lane & 15, quad = lane >> 4;
    const int q0 = blockIdx.x * 128;

    __shared__ bf16_t Kf[2][4096];
    __shared__ bf16_t Vf[2][4096];

    // Q B-frags for this wave's two 16-query groups
    bf16x8 qf[2][2];
    #pragma unroll
    for (int g = 0; g < 2; g++) {
        const int q0g = q0 + wid * 32 + g * 16;
        const bf16_t* qrow = qbuf + ((size_t)h * 4096 + q0g + ln) * 64;
        qf[g][0] = *(const bf16x8*)(qrow + quad * 8);
        qf[g][1] = *(const bf16x8*)(qrow + 32 + quad * 8);
    }

    // all-ones A fragment for the l row-sum MFMA
    bf16x8 ones;
    #pragma unroll
    for (int i = 0; i < 8; i++) ones[i] = (bf16_t)1.0f;

    const bf16_t* kg = kswz + (size_t)h * 64 * 4096 + (size_t)chunk * 32 * 4096;
    const bf16_t* vg = vswz + (size_t)h * 64 * 4096 + (size_t)chunk * 32 * 4096;

    f32x4 accO[2][4];
    f32x4 accL[2];
    #pragma unroll
    for (int g = 0; g < 2; g++) {
        accL[g] = {0.f, 0.f, 0.f, 0.f};
        #pragma unroll
        for (int d = 0; d < 4; d++) accO[g][d] = {0.f, 0.f, 0.f, 0.f};
    }

    // stage one 8KB K + 8KB V tile; 4 waves cover it: 2 K + 2 V glds per wave
    auto stage = [&](int tile, int buf) {
        const bf16_t* kt_g = kg + (size_t)tile * 4096;
        const bf16_t* vt_g = vg + (size_t)tile * 4096;
        #pragma unroll
        for (int i = 0; i < 2; i++) {
            glds16(kt_g + wid * 1024 + i * 512 + lane * 8, &Kf[buf][wid * 1024 + i * 512]);
            glds16(vt_g + wid * 1024 + i * 512 + lane * 8, &Vf[buf][wid * 1024 + i * 512]);
        }
    };

    auto compute = [&](const bf16_t* Kb, const bf16_t* Vb) {
        #pragma unroll
        for (int m = 0; m < 2; m++) {        // m-pair = 32 keys
            bf16x8 vf[4];
            #pragma unroll
            for (int db = 0; db < 4; db++)
                vf[db] = *(const bf16x8*)(Vb + m * 2048 + db * 512 + lane * 8);
            bf16x8 kfa0 = *(const bf16x8*)(Kb + (2 * m) * 1024 + lane * 8);
            bf16x8 kfa1 = *(const bf16x8*)(Kb + (2 * m) * 1024 + 512 + lane * 8);
            bf16x8 kfb0 = *(const bf16x8*)(Kb + (2 * m + 1) * 1024 + lane * 8);
            bf16x8 kfb1 = *(const bf16x8*)(Kb + (2 * m + 1) * 1024 + 512 + lane * 8);
            #pragma unroll
            for (int g = 0; g < 2; g++) {
                f32x4 z = {0.f, 0.f, 0.f, 0.f};
                f32x4 SA = __builtin_amdgcn_mfma_f32_16x16x32_bf16(kfa0, qf[g][0], z, 0, 0, 0);
                SA = __builtin_amdgcn_mfma_f32_16x16x32_bf16(kfa1, qf[g][1], SA, 0, 0, 0);
                f32x4 SB = __builtin_amdgcn_mfma_f32_16x16x32_bf16(kfb0, qf[g][0], z, 0, 0, 0);
                SB = __builtin_amdgcn_mfma_f32_16x16x32_bf16(kfb1, qf[g][1], SB, 0, 0, 0);

                float e0 = hwexp2(SA[0]), e1 = hwexp2(SA[1]), e2 = hwexp2(SA[2]), e3 = hwexp2(SA[3]);
                float e4 = hwexp2(SB[0]), e5 = hwexp2(SB[1]), e6 = hwexp2(SB[2]), e7 = hwexp2(SB[3]);
                uint4v u = {pack_trunc(e0, e1), pack_trunc(e2, e3),
                            pack_trunc(e4, e5), pack_trunc(e6, e7)};
                bf16x8 pb = __builtin_bit_cast(bf16x8, u);
                accL[g] = __builtin_amdgcn_mfma_f32_16x16x32_bf16(ones, pb, accL[g], 0, 0, 0);
                #pragma unroll
                for (int db = 0; db < 4; db++)
                    accO[g][db] = __builtin_amdgcn_mfma_f32_16x16x32_bf16(vf[db], pb, accO[g][db], 0, 0, 0);
            }
        }
    };

    stage(0, 0);

    for (int kt = 0; kt < 32; kt += 2) {
        __builtin_amdgcn_s_barrier();                 // prev reads of buf1 done
        stage(kt + 1, 1);
        __builtin_amdgcn_s_waitcnt(0x0F74);           // vmcnt(4): tile kt resident
        __builtin_amdgcn_s_barrier();
        compute(&Kf[0][0], &Vf[0][0]);
        __builtin_amdgcn_s_barrier();                 // prev reads of buf0 done
        if (kt + 2 < 32) {
            stage(kt + 2, 0);
            __builtin_amdgcn_s_waitcnt(0x0F74);       // vmcnt(4)
        } else {
            __builtin_amdgcn_s_waitcnt(0x0F70);       // vmcnt(0)
        }
        __builtin_amdgcn_s_barrier();
        compute(&Kf[1][0], &Vf[1][0]);
    }

    float* base = chunk ? raw1 : raw0;
    #pragma unroll
    for (int g = 0; g < 2; g++) {
        // every lane's accL[g][0] holds l[q=ln] (rows identical for ones-A)
        const int qg = q0 + wid * 32 + g * 16 + ln;
        if (quad == 0) l_part[(size_t)chunk * 49152 + h * 4096 + qg] = accL[g][0];
        float* op = base + (size_t)qg * 768 + h * 64 + quad * 4;
        #pragma unroll
        for (int db = 0; db < 4; db++)
            *(f32x4*)(op + db * 16) = accO[g][db];
    }
}

// ---------------------------------------------------------------------------
// Normalize + combine: out[q,c] = (raw0[q,c] + raw1[q,c]) / (l0[h][q]+l1[h][q])
// raw1 aliases out (d_out scratch) — element-wise read-then-write, safe.
// ---------------------------------------------------------------------------
__global__ __launch_bounds__(256) void norm_kernel(const float* __restrict__ raw0,
                                                   const float* __restrict__ raw1,
                                                   const float* __restrict__ l_part,
                                                   float* __restrict__ out) {
    const int q = blockIdx.x;
    const int tid = threadIdx.x;
    __shared__ float linv[12];
    if (tid < 12)
        linv[tid] = 1.0f / (l_part[tid * 4096 + q] + l_part[49152 + tid * 4096 + q]);
    __syncthreads();
    #pragma unroll
    for (int t = 0; t < 3; t++) {
        int c = tid + t * 256;
        size_t idx = (size_t)q * 768 + c;
        out[idx] = (raw0[idx] + raw1[idx]) * linv[c >> 6];
    }
}

// ---------------------------------------------------------------------------
extern "C" void kernel_launch(void* const* d_in, const int* in_sizes, int n_in,
                              void* d_out, int out_size, void* d_ws, size_t ws_size,
                              hipStream_t stream) {
    const float* x      = (const float*)d_in[0];
    const float* proj_w = (const float*)d_in[1];
    const float* proj_b = (const float*)d_in[2];
    const float* ln_g   = (const float*)d_in[3];
    const float* ln_b   = (const float*)d_in[4];
    const float* qkv_w  = (const float*)d_in[5];
    float* out = (float*)d_out;

    char* ws = (char*)d_ws;
    float*  tok_pre = (float*)(ws + 0);              // 12,582,912 B (reused: raw0)
    bf16_t* tok_b   = (bf16_t*)(ws + 12582912);      //  6,291,456 B
    bf16_t* pw_b    = (bf16_t*)(ws + 18874368);      //    393,216 B (reused: l_part)
    bf16_t* qw_b    = (bf16_t*)(ws + 19267584);      //  3,538,944 B
    bf16_t* qbuf    = (bf16_t*)(ws + 22806528);      //  6,291,456 B
    bf16_t* kswz    = (bf16_t*)(ws + 29097984);      //  6,291,456 B
    bf16_t* vswz    = (bf16_t*)(ws + 35389440);      //  6,291,456 B (total ~41.7 MB)
    float*  raw0    = tok_pre;                       // dead after ln_kernel
    float*  raw1    = out;                           // d_out used as chunk-1 scratch
    float*  l_part  = (float*)pw_b;                  // dead after patch_gemm

    cvt2_kernel<<<1920, 256, 0, stream>>>(proj_w, pw_b, 49152, qkv_w, qw_b, 442368);
    patch_gemm<<<dim3(64, 12), 256, 0, stream>>>(x, pw_b, proj_b, tok_pre);
    ln_kernel<<<4096, 256, 0, stream>>>(tok_pre, ln_g, ln_b, tok_b);
    qkv_gemm<<<dim3(32, 18), 256, 0, stream>>>(tok_b, qw_b, qbuf, kswz, vswz);
    attn_partial<<<dim3(32, 12, 2), 256, 0, stream>>>(qbuf, kswz, vswz, raw0, raw1, l_part);
    norm_kernel<<<4096, 256, 0, stream>>>(raw0, raw1, l_part, out);
}

// Round 13
// 178.952 us; speedup vs baseline: 1.9215x; 1.0565x over previous
//
#include <hip/hip_runtime.h>
#include <hip/hip_bf16.h>

typedef __bf16 bf16_t;
typedef __attribute__((ext_vector_type(8))) __bf16 bf16x8;
typedef __attribute__((ext_vector_type(4))) __bf16 bf16x4;
typedef __attribute__((ext_vector_type(4))) float f32x4;
typedef __attribute__((ext_vector_type(4))) unsigned int uint4v;

#define QSCALE 0.1803368801111204f  /* 0.125 * log2(e) */

// async global->LDS, 16B per lane; LDS dst = wave-uniform base + lane*16
static __device__ inline void glds16(const bf16_t* g, bf16_t* l) {
    __builtin_amdgcn_global_load_lds(
        (__attribute__((address_space(1))) const void*)g,
        (__attribute__((address_space(3))) void*)l,
        16, 0, 0);
}

// raw hardware v_exp_f32 (input bounded — no libm range/denorm fixup needed)
static __device__ inline float hwexp2(float x) {
#if __has_builtin(__builtin_amdgcn_exp2f)
    return __builtin_amdgcn_exp2f(x);
#else
    float r;
    asm("v_exp_f32 %0, %1" : "=v"(r) : "v"(x));
    return r;
#endif
}

// pack two fp32 -> bf16x2 by truncation (top 16 bits), single v_perm_b32
static __device__ inline unsigned int pack_trunc(float lo, float hi) {
    return __builtin_amdgcn_perm(__builtin_bit_cast(unsigned int, hi),
                                 __builtin_bit_cast(unsigned int, lo),
                                 0x07060302u);
}

// ---------------------------------------------------------------------------
// fused fp32 -> bf16 convert for both weight tensors (one launch)
// ---------------------------------------------------------------------------
__global__ void cvt2_kernel(const float* __restrict__ a, bf16_t* __restrict__ oa, int na4,
                            const float* __restrict__ b, bf16_t* __restrict__ ob, int nb4) {
    int i = blockIdx.x * 256 + threadIdx.x;
    if (i < na4) {
        float4 v = ((const float4*)a)[i];
        bf16x4 o = {(bf16_t)v.x, (bf16_t)v.y, (bf16_t)v.z, (bf16_t)v.w};
        ((bf16x4*)oa)[i] = o;
    } else {
        int j = i - na4;
        if (j < nb4) {
            float4 v = ((const float4*)b)[j];
            bf16x4 o = {(bf16_t)v.x, (bf16_t)v.y, (bf16_t)v.z, (bf16_t)v.w};
            ((bf16x4*)ob)[j] = o;
        }
    }
}

// ---------------------------------------------------------------------------
// Patch-embed GEMM: tok[4096,768] = patches[4096,256] @ proj_w[768,256]^T + b
// ---------------------------------------------------------------------------
__global__ __launch_bounds__(256) void patch_gemm(const float* __restrict__ x,
                                                  const bf16_t* __restrict__ pw,
                                                  const float* __restrict__ pb,
                                                  float* __restrict__ tok) {
    const int bm = blockIdx.x;
    const int bn = blockIdx.y;
    const int tid = threadIdx.x;

    __shared__ bf16_t At[64][264];
    __shared__ bf16_t Bt[64][264];

    #pragma unroll
    for (int t = 0; t < 16; t++) {
        int linear = tid + t * 256;
        int ml = linear >> 6;
        int kv = (linear & 63) << 2;
        int n = bm * 64 + ml;
        int pr = n >> 6, pc = n & 63;
        int i = kv >> 4, j = kv & 15;
        float4 v = *(const float4*)(x + (pr * 16 + i) * 1024 + pc * 16 + j);
        bf16x4 o = {(bf16_t)v.x, (bf16_t)v.y, (bf16_t)v.z, (bf16_t)v.w};
        *(bf16x4*)(&At[ml][kv]) = o;
    }
    #pragma unroll
    for (int t = 0; t < 8; t++) {
        int linear = tid + t * 256;
        int nl = linear >> 5;
        int kv = (linear & 31) << 3;
        *(int4*)(&Bt[nl][kv]) = *(const int4*)(pw + (size_t)(bn * 64 + nl) * 256 + kv);
    }
    __syncthreads();

    const int lane = tid & 63, wid = tid >> 6, ln = lane & 15, quad = lane >> 4;
    f32x4 acc[4];
    #pragma unroll
    for (int s = 0; s < 4; s++) acc[s] = {0.f, 0.f, 0.f, 0.f};

    #pragma unroll
    for (int kk = 0; kk < 8; kk++) {
        bf16x8 af = *(const bf16x8*)(&At[wid * 16 + ln][kk * 32 + quad * 8]);
        #pragma unroll
        for (int s = 0; s < 4; s++) {
            bf16x8 bfr = *(const bf16x8*)(&Bt[s * 16 + ln][kk * 32 + quad * 8]);
            acc[s] = __builtin_amdgcn_mfma_f32_16x16x32_bf16(af, bfr, acc[s], 0, 0, 0);
        }
    }

    #pragma unroll
    for (int s = 0; s < 4; s++) {
        int e = bn * 64 + s * 16 + ln;
        float bias = pb[e];
        #pragma unroll
        for (int r = 0; r < 4; r++) {
            int m = bm * 64 + wid * 16 + quad * 4 + r;
            tok[(size_t)m * 768 + e] = acc[s][r] + bias;
        }
    }
}

// ---------------------------------------------------------------------------
// LayerNorm per token (768), fp32 stats, bf16 out.
// ---------------------------------------------------------------------------
__global__ __launch_bounds__(256) void ln_kernel(const float* __restrict__ tok,
                                                 const float* __restrict__ g,
                                                 const float* __restrict__ b,
                                                 bf16_t* __restrict__ out) {
    const int n = blockIdx.x;
    const int tid = threadIdx.x;
    const float* row = tok + (size_t)n * 768;
    float x0 = row[tid], x1 = row[tid + 256], x2 = row[tid + 512];
    float s = x0 + x1 + x2;
    float s2 = x0 * x0 + x1 * x1 + x2 * x2;
    #pragma unroll
    for (int off = 32; off; off >>= 1) {
        s += __shfl_xor(s, off);
        s2 += __shfl_xor(s2, off);
    }
    __shared__ float ws1[4], ws2[4];
    int wid = tid >> 6;
    if ((tid & 63) == 0) { ws1[wid] = s; ws2[wid] = s2; }
    __syncthreads();
    s = ws1[0] + ws1[1] + ws1[2] + ws1[3];
    s2 = ws2[0] + ws2[1] + ws2[2] + ws2[3];
    float mu = s * (1.f / 768.f);
    float var = s2 * (1.f / 768.f) - mu * mu;
    float r = rsqrtf(var + 1e-6f);
    bf16_t* orow = out + (size_t)n * 768;
    orow[tid]       = (bf16_t)((x0 - mu) * r * g[tid]       + b[tid]);
    orow[tid + 256] = (bf16_t)((x1 - mu) * r * g[tid + 256] + b[tid + 256]);
    orow[tid + 512] = (bf16_t)((x2 - mu) * r * g[tid + 512] + b[tid + 512]);
}

// ---------------------------------------------------------------------------
// QKV GEMM v3: 128(M)x64(N) tile, BK=64, async dbuf glds16 staging with
// XOR-swizzled LDS (chunk c of row r lives at slot c^(r&7) -> conflict-free
// ds_read_b128 AND contiguous async writes). Grid (32, 36); 4 waves in 2x2
// (wm: 64-row half, wn: 32-col half); acc 4x2 f32x4 per wave.
// bn: 0..11 = q-heads, 12..23 = k, 24..35 = v. Same scatter swizzles as v1.
// ---------------------------------------------------------------------------
__global__ __launch_bounds__(256) void qkv_gemm(const bf16_t* __restrict__ tokb,
                                                const bf16_t* __restrict__ wq,
                                                bf16_t* __restrict__ qb,
                                                bf16_t* __restrict__ kswz,
                                                bf16_t* __restrict__ vswz) {
    const int bm = blockIdx.x;   // 32 m-tiles (128 tokens)
    const int bn = blockIdx.y;   // 36 n-tiles (64 cols = one head of q/k/v)
    const int tid = threadIdx.x;
    const int wid = tid >> 6, lane = tid & 63;
    const int ln = lane & 15, quad = lane >> 4;
    const int wm = wid & 1, wn = wid >> 1;

    __shared__ bf16_t Asw[2][8192];   // 128 rows x 8 chunks x 8 bf16
    __shared__ bf16_t Bsw[2][4096];   // 64 rows x 8 chunks

    f32x4 acc[4][2];
    #pragma unroll
    for (int sm = 0; sm < 4; sm++)
        #pragma unroll
        for (int sn = 0; sn < 2; sn++) acc[sm][sn] = {0.f, 0.f, 0.f, 0.f};

    // staging: per wave, A chunks [wid*256, +256) (4 issues), B [wid*128, +128) (2)
    auto stage = [&](int kb0, int buf) {
        #pragma unroll
        for (int i = 0; i < 4; i++) {
            int L = wid * 256 + i * 64 + lane;
            int r = L >> 3, c = L & 7;
            int gc = c ^ (r & 7);
            glds16(tokb + (size_t)(bm * 128 + r) * 768 + kb0 + gc * 8,
                   Asw[buf] + (wid * 256 + i * 64) * 8);
        }
        #pragma unroll
        for (int i = 0; i < 2; i++) {
            int L = wid * 128 + i * 64 + lane;
            int r = L >> 3, c = L & 7;
            int gc = c ^ (r & 7);
            glds16(wq + (size_t)(bn * 64 + r) * 768 + kb0 + gc * 8,
                   Bsw[buf] + (wid * 128 + i * 64) * 8);
        }
    };

    auto compute = [&](const bf16_t* Ab, const bf16_t* Bb) {
        #pragma unroll
        for (int kk = 0; kk < 2; kk++) {
            const int c = (kk * 4 + quad) ^ (ln & 7);
            bf16x8 af[4], bfr[2];
            #pragma unroll
            for (int sm = 0; sm < 4; sm++) {
                int row = wm * 64 + sm * 16 + ln;
                af[sm] = *(const bf16x8*)(Ab + (row * 8 + c) * 8);
            }
            #pragma unroll
            for (int sn = 0; sn < 2; sn++) {
                int row = wn * 32 + sn * 16 + ln;
                bfr[sn] = *(const bf16x8*)(Bb + (row * 8 + c) * 8);
            }
            #pragma unroll
            for (int sm = 0; sm < 4; sm++)
                #pragma unroll
                for (int sn = 0; sn < 2; sn++)
                    acc[sm][sn] = __builtin_amdgcn_mfma_f32_16x16x32_bf16(af[sm], bfr[sn], acc[sm][sn], 0, 0, 0);
        }
    };

    stage(0, 0);

    for (int s = 0; s < 12; s += 2) {
        __builtin_amdgcn_s_barrier();                 // prev reads of buf1 done
        stage((s + 1) * 64, 1);
        __builtin_amdgcn_s_waitcnt(0x0F76);           // vmcnt(6): buf0 resident
        __builtin_amdgcn_s_barrier();
        compute(Asw[0], Bsw[0]);
        __builtin_amdgcn_s_barrier();                 // prev reads of buf0 done
        if (s + 2 < 12) {
            stage((s + 2) * 64, 0);
            __builtin_amdgcn_s_waitcnt(0x0F76);       // vmcnt(6)
        } else {
            __builtin_amdgcn_s_waitcnt(0x0F70);       // vmcnt(0)
        }
        __builtin_amdgcn_s_barrier();
        compute(Asw[1], Bsw[1]);
    }

    const int sidx = bn / 12;                  // 0=q 1=k 2=v (block-uniform)
    const int head = bn % 12;
    #pragma unroll
    for (int sn = 0; sn < 2; sn++) {
        int dc = wn * 32 + sn * 16 + ln;       // 0..63 within head
        #pragma unroll
        for (int sm = 0; sm < 4; sm++) {
            #pragma unroll
            for (int r = 0; r < 4; r++) {
                int m = bm * 128 + wm * 64 + sm * 16 + quad * 4 + r;   // token = key
                float v = acc[sm][sn][r];
                if (sidx == 0) {
                    qb[((size_t)(head * 4096 + m)) * 64 + dc] = (bf16_t)(v * QSCALE);
                } else if (sidx == 1) {
                    bf16_t val = (bf16_t)v;
                    int kt = m >> 6, sb = (m >> 4) & 3, lnk = m & 15;
                    int half = dc >> 5, quadk = (dc >> 3) & 3, j = dc & 7;
                    int l = quadk * 16 + lnk;
                    kswz[((size_t)(head * 64 + kt)) * 4096 + sb * 1024 + half * 512 + l * 8 + j] = val;
                } else {
                    bf16_t val = (bf16_t)v;
                    int kt = m >> 6, keyl = m & 63;
                    int sblk = keyl >> 4;
                    int mm = sblk >> 1, tb = sblk & 1;
                    int w16 = keyl & 15, qv = w16 >> 2, jj = w16 & 3;
                    int jp = tb * 4 + jj;
                    int db = dc >> 4, lnv = dc & 15;
                    int l = qv * 16 + lnv;
                    vswz[((size_t)(head * 64 + kt)) * 4096 + ((mm * 4 + db) * 64 + l) * 8 + jp] = val;
                }
            }
        }
    }
}

// ---------------------------------------------------------------------------
// Attention: split-K=2, no atomics, async dbuf glds pipeline, raw v_exp_f32,
// perm-truncated P pack, l via ones-MFMA.
// Grid: (32, 12, 2), 256 threads = 4 waves x 32 q.
// ---------------------------------------------------------------------------
__global__ __launch_bounds__(256, 2) void attn_partial(const bf16_t* __restrict__ qbuf,
                                                       const bf16_t* __restrict__ kswz,
                                                       const bf16_t* __restrict__ vswz,
                                                       float* __restrict__ raw0,
                                                       float* __restrict__ raw1,
                                                       float* __restrict__ l_part) {
    const int h = blockIdx.y;
    const int chunk = blockIdx.z;
    const int tid = threadIdx.x;
    const int wid = tid >> 6;           // 0..3
    const int lane = tid & 63;
    const int ln = lane & 15, quad = lane >> 4;
    const int q0 = blockIdx.x * 128;

    __shared__ bf16_t Kf[2][4096];
    __shared__ bf16_t Vf[2][4096];

    // Q B-frags for this wave's two 16-query groups
    bf16x8 qf[2][2];
    #pragma unroll
    for (int g = 0; g < 2; g++) {
        const int q0g = q0 + wid * 32 + g * 16;
        const bf16_t* qrow = qbuf + ((size_t)h * 4096 + q0g + ln) * 64;
        qf[g][0] = *(const bf16x8*)(qrow + quad * 8);
        qf[g][1] = *(const bf16x8*)(qrow + 32 + quad * 8);
    }

    // all-ones A fragment for the l row-sum MFMA
    bf16x8 ones;
    #pragma unroll
    for (int i = 0; i < 8; i++) ones[i] = (bf16_t)1.0f;

    const bf16_t* kg = kswz + (size_t)h * 64 * 4096 + (size_t)chunk * 32 * 4096;
    const bf16_t* vg = vswz + (size_t)h * 64 * 4096 + (size_t)chunk * 32 * 4096;

    f32x4 accO[2][4];
    f32x4 accL[2];
    #pragma unroll
    for (int g = 0; g < 2; g++) {
        accL[g] = {0.f, 0.f, 0.f, 0.f};
        #pragma unroll
        for (int d = 0; d < 4; d++) accO[g][d] = {0.f, 0.f, 0.f, 0.f};
    }

    // stage one 8KB K + 8KB V tile; 4 waves cover it: 2 K + 2 V glds per wave
    auto stage = [&](int tile, int buf) {
        const bf16_t* kt_g = kg + (size_t)tile * 4096;
        const bf16_t* vt_g = vg + (size_t)tile * 4096;
        #pragma unroll
        for (int i = 0; i < 2; i++) {
            glds16(kt_g + wid * 1024 + i * 512 + lane * 8, &Kf[buf][wid * 1024 + i * 512]);
            glds16(vt_g + wid * 1024 + i * 512 + lane * 8, &Vf[buf][wid * 1024 + i * 512]);
        }
    };

    auto compute = [&](const bf16_t* Kb, const bf16_t* Vb) {
        #pragma unroll
        for (int m = 0; m < 2; m++) {        // m-pair = 32 keys
            bf16x8 vf[4];
            #pragma unroll
            for (int db = 0; db < 4; db++)
                vf[db] = *(const bf16x8*)(Vb + m * 2048 + db * 512 + lane * 8);
            bf16x8 kfa0 = *(const bf16x8*)(Kb + (2 * m) * 1024 + lane * 8);
            bf16x8 kfa1 = *(const bf16x8*)(Kb + (2 * m) * 1024 + 512 + lane * 8);
            bf16x8 kfb0 = *(const bf16x8*)(Kb + (2 * m + 1) * 1024 + lane * 8);
            bf16x8 kfb1 = *(const bf16x8*)(Kb + (2 * m + 1) * 1024 + 512 + lane * 8);
            #pragma unroll
            for (int g = 0; g < 2; g++) {
                f32x4 z = {0.f, 0.f, 0.f, 0.f};
                f32x4 SA = __builtin_amdgcn_mfma_f32_16x16x32_bf16(kfa0, qf[g][0], z, 0, 0, 0);
                SA = __builtin_amdgcn_mfma_f32_16x16x32_bf16(kfa1, qf[g][1], SA, 0, 0, 0);
                f32x4 SB = __builtin_amdgcn_mfma_f32_16x16x32_bf16(kfb0, qf[g][0], z, 0, 0, 0);
                SB = __builtin_amdgcn_mfma_f32_16x16x32_bf16(kfb1, qf[g][1], SB, 0, 0, 0);

                float e0 = hwexp2(SA[0]), e1 = hwexp2(SA[1]), e2 = hwexp2(SA[2]), e3 = hwexp2(SA[3]);
                float e4 = hwexp2(SB[0]), e5 = hwexp2(SB[1]), e6 = hwexp2(SB[2]), e7 = hwexp2(SB[3]);
                uint4v u = {pack_trunc(e0, e1), pack_trunc(e2, e3),
                            pack_trunc(e4, e5), pack_trunc(e6, e7)};
                bf16x8 pb = __builtin_bit_cast(bf16x8, u);
                accL[g] = __builtin_amdgcn_mfma_f32_16x16x32_bf16(ones, pb, accL[g], 0, 0, 0);
                #pragma unroll
                for (int db = 0; db < 4; db++)
                    accO[g][db] = __builtin_amdgcn_mfma_f32_16x16x32_bf16(vf[db], pb, accO[g][db], 0, 0, 0);
            }
        }
    };

    stage(0, 0);

    for (int kt = 0; kt < 32; kt += 2) {
        __builtin_amdgcn_s_barrier();                 // prev reads of buf1 done
        stage(kt + 1, 1);
        __builtin_amdgcn_s_waitcnt(0x0F74);           // vmcnt(4): tile kt resident
        __builtin_amdgcn_s_barrier();
        compute(&Kf[0][0], &Vf[0][0]);
        __builtin_amdgcn_s_barrier();                 // prev reads of buf0 done
        if (kt + 2 < 32) {
            stage(kt + 2, 0);
            __builtin_amdgcn_s_waitcnt(0x0F74);       // vmcnt(4)
        } else {
            __builtin_amdgcn_s_waitcnt(0x0F70);       // vmcnt(0)
        }
        __builtin_amdgcn_s_barrier();
        compute(&Kf[1][0], &Vf[1][0]);
    }

    float* base = chunk ? raw1 : raw0;
    #pragma unroll
    for (int g = 0; g < 2; g++) {
        // every lane's accL[g][0] holds l[q=ln] (rows identical for ones-A)
        const int qg = q0 + wid * 32 + g * 16 + ln;
        if (quad == 0) l_part[(size_t)chunk * 49152 + h * 4096 + qg] = accL[g][0];
        float* op = base + (size_t)qg * 768 + h * 64 + quad * 4;
        #pragma unroll
        for (int db = 0; db < 4; db++)
            *(f32x4*)(op + db * 16) = accO[g][db];
    }
}

// ---------------------------------------------------------------------------
// Normalize + combine: out[q,c] = (raw0[q,c] + raw1[q,c]) / (l0[h][q]+l1[h][q])
// raw1 aliases out (d_out scratch) — element-wise read-then-write, safe.
// ---------------------------------------------------------------------------
__global__ __launch_bounds__(256) void norm_kernel(const float* __restrict__ raw0,
                                                   const float* __restrict__ raw1,
                                                   const float* __restrict__ l_part,
                                                   float* __restrict__ out) {
    const int q = blockIdx.x;
    const int tid = threadIdx.x;
    __shared__ float linv[12];
    if (tid < 12)
        linv[tid] = 1.0f / (l_part[tid * 4096 + q] + l_part[49152 + tid * 4096 + q]);
    __syncthreads();
    #pragma unroll
    for (int t = 0; t < 3; t++) {
        int c = tid + t * 256;
        size_t idx = (size_t)q * 768 + c;
        out[idx] = (raw0[idx] + raw1[idx]) * linv[c >> 6];
    }
}

// ---------------------------------------------------------------------------
extern "C" void kernel_launch(void* const* d_in, const int* in_sizes, int n_in,
                              void* d_out, int out_size, void* d_ws, size_t ws_size,
                              hipStream_t stream) {
    const float* x      = (const float*)d_in[0];
    const float* proj_w = (const float*)d_in[1];
    const float* proj_b = (const float*)d_in[2];
    const float* ln_g   = (const float*)d_in[3];
    const float* ln_b   = (const float*)d_in[4];
    const float* qkv_w  = (const float*)d_in[5];
    float* out = (float*)d_out;

    char* ws = (char*)d_ws;
    float*  tok_pre = (float*)(ws + 0);              // 12,582,912 B (reused: raw0)
    bf16_t* tok_b   = (bf16_t*)(ws + 12582912);      //  6,291,456 B
    bf16_t* pw_b    = (bf16_t*)(ws + 18874368);      //    393,216 B (reused: l_part)
    bf16_t* qw_b    = (bf16_t*)(ws + 19267584);      //  3,538,944 B
    bf16_t* qbuf    = (bf16_t*)(ws + 22806528);      //  6,291,456 B
    bf16_t* kswz    = (bf16_t*)(ws + 29097984);      //  6,291,456 B
    bf16_t* vswz    = (bf16_t*)(ws + 35389440);      //  6,291,456 B (total ~41.7 MB)
    float*  raw0    = tok_pre;                       // dead after ln_kernel
    float*  raw1    = out;                           // d_out used as chunk-1 scratch
    float*  l_part  = (float*)pw_b;                  // dead after patch_gemm

    cvt2_kernel<<<1920, 256, 0, stream>>>(proj_w, pw_b, 49152, qkv_w, qw_b, 442368);
    patch_gemm<<<dim3(64, 12), 256, 0, stream>>>(x, pw_b, proj_b, tok_pre);
    ln_kernel<<<4096, 256, 0, stream>>>(tok_pre, ln_g, ln_b, tok_b);
    qkv_gemm<<<dim3(32, 36), 256, 0, stream>>>(tok_b, qw_b, qbuf, kswz, vswz);
    attn_partial<<<dim3(32, 12, 2), 256, 0, stream>>>(qbuf, kswz, vswz, raw0, raw1, l_part);
    norm_kernel<<<4096, 256, 0, stream>>>(raw0, raw1, l_part, out);
}

// Round 14
// 178.152 us; speedup vs baseline: 1.9301x; 1.0045x over previous
//
#include <hip/hip_runtime.h>
#include <hip/hip_bf16.h>

typedef __bf16 bf16_t;
typedef __attribute__((ext_vector_type(8))) __bf16 bf16x8;
typedef __attribute__((ext_vector_type(4))) __bf16 bf16x4;
typedef __attribute__((ext_vector_type(4))) float f32x4;
typedef __attribute__((ext_vector_type(4))) unsigned int uint4v;

#define QSCALE 0.1803368801111204f  /* 0.125 * log2(e) */

// async global->LDS, 16B per lane; LDS dst = wave-uniform base + lane*16
static __device__ inline void glds16(const bf16_t* g, bf16_t* l) {
    __builtin_amdgcn_global_load_lds(
        (__attribute__((address_space(1))) const void*)g,
        (__attribute__((address_space(3))) void*)l,
        16, 0, 0);
}

// raw hardware v_exp_f32 (input bounded — no libm range/denorm fixup needed)
static __device__ inline float hwexp2(float x) {
#if __has_builtin(__builtin_amdgcn_exp2f)
    return __builtin_amdgcn_exp2f(x);
#else
    float r;
    asm("v_exp_f32 %0, %1" : "=v"(r) : "v"(x));
    return r;
#endif
}

// pack two fp32 -> bf16x2 by truncation (top 16 bits), single v_perm_b32
static __device__ inline unsigned int pack_trunc(float lo, float hi) {
    return __builtin_amdgcn_perm(__builtin_bit_cast(unsigned int, hi),
                                 __builtin_bit_cast(unsigned int, lo),
                                 0x07060302u);
}

// ---------------------------------------------------------------------------
// fp32 -> bf16 convert (qkv_w only; proj_w conversion fused into patch_gemm)
// ---------------------------------------------------------------------------
__global__ void cvt_kernel(const float* __restrict__ in, bf16_t* __restrict__ out, int n4) {
    int i = blockIdx.x * 256 + threadIdx.x;
    if (i < n4) {
        float4 v = ((const float4*)in)[i];
        bf16x4 o = {(bf16_t)v.x, (bf16_t)v.y, (bf16_t)v.z, (bf16_t)v.w};
        ((bf16x4*)out)[i] = o;
    }
}

// ---------------------------------------------------------------------------
// Patch-embed GEMM: tok[4096,768] = patches[4096,256] @ proj_w[768,256]^T + b
// Grid (12, 64): bn = blockIdx.x (fastest) -> consecutive blocks share the
// A (patch) tile; proj_w fp32 (786 KB) stays L2-resident. fp32->bf16 for B
// fused into staging.
// ---------------------------------------------------------------------------
__global__ __launch_bounds__(256) void patch_gemm(const float* __restrict__ x,
                                                  const float* __restrict__ pw,
                                                  const float* __restrict__ pb,
                                                  float* __restrict__ tok) {
    const int bn = blockIdx.x;   // 12 embed tiles
    const int bm = blockIdx.y;   // 64 token tiles
    const int tid = threadIdx.x;

    __shared__ bf16_t At[64][264];
    __shared__ bf16_t Bt[64][264];

    #pragma unroll
    for (int t = 0; t < 16; t++) {
        int linear = tid + t * 256;
        int ml = linear >> 6;
        int kv = (linear & 63) << 2;
        int n = bm * 64 + ml;
        int pr = n >> 6, pc = n & 63;
        int i = kv >> 4, j = kv & 15;
        float4 v = *(const float4*)(x + (pr * 16 + i) * 1024 + pc * 16 + j);
        bf16x4 o = {(bf16_t)v.x, (bf16_t)v.y, (bf16_t)v.z, (bf16_t)v.w};
        *(bf16x4*)(&At[ml][kv]) = o;
    }
    #pragma unroll
    for (int t = 0; t < 8; t++) {
        int linear = tid + t * 256;
        int nl = linear >> 5;
        int kv = (linear & 31) << 3;
        const float* src = pw + (size_t)(bn * 64 + nl) * 256 + kv;
        float4 v0 = *(const float4*)(src);
        float4 v1 = *(const float4*)(src + 4);
        bf16x8 o = {(bf16_t)v0.x, (bf16_t)v0.y, (bf16_t)v0.z, (bf16_t)v0.w,
                    (bf16_t)v1.x, (bf16_t)v1.y, (bf16_t)v1.z, (bf16_t)v1.w};
        *(bf16x8*)(&Bt[nl][kv]) = o;
    }
    __syncthreads();

    const int lane = tid & 63, wid = tid >> 6, ln = lane & 15, quad = lane >> 4;
    f32x4 acc[4];
    #pragma unroll
    for (int s = 0; s < 4; s++) acc[s] = {0.f, 0.f, 0.f, 0.f};

    #pragma unroll
    for (int kk = 0; kk < 8; kk++) {
        bf16x8 af = *(const bf16x8*)(&At[wid * 16 + ln][kk * 32 + quad * 8]);
        #pragma unroll
        for (int s = 0; s < 4; s++) {
            bf16x8 bfr = *(const bf16x8*)(&Bt[s * 16 + ln][kk * 32 + quad * 8]);
            acc[s] = __builtin_amdgcn_mfma_f32_16x16x32_bf16(af, bfr, acc[s], 0, 0, 0);
        }
    }

    #pragma unroll
    for (int s = 0; s < 4; s++) {
        int e = bn * 64 + s * 16 + ln;
        float bias = pb[e];
        #pragma unroll
        for (int r = 0; r < 4; r++) {
            int m = bm * 64 + wid * 16 + quad * 4 + r;
            tok[(size_t)m * 768 + e] = acc[s][r] + bias;
        }
    }
}

// ---------------------------------------------------------------------------
// LayerNorm per token (768), fp32 stats, bf16 out.
// ---------------------------------------------------------------------------
__global__ __launch_bounds__(256) void ln_kernel(const float* __restrict__ tok,
                                                 const float* __restrict__ g,
                                                 const float* __restrict__ b,
                                                 bf16_t* __restrict__ out) {
    const int n = blockIdx.x;
    const int tid = threadIdx.x;
    const float* row = tok + (size_t)n * 768;
    float x0 = row[tid], x1 = row[tid + 256], x2 = row[tid + 512];
    float s = x0 + x1 + x2;
    float s2 = x0 * x0 + x1 * x1 + x2 * x2;
    #pragma unroll
    for (int off = 32; off; off >>= 1) {
        s += __shfl_xor(s, off);
        s2 += __shfl_xor(s2, off);
    }
    __shared__ float ws1[4], ws2[4];
    int wid = tid >> 6;
    if ((tid & 63) == 0) { ws1[wid] = s; ws2[wid] = s2; }
    __syncthreads();
    s = ws1[0] + ws1[1] + ws1[2] + ws1[3];
    s2 = ws2[0] + ws2[1] + ws2[2] + ws2[3];
    float mu = s * (1.f / 768.f);
    float var = s2 * (1.f / 768.f) - mu * mu;
    float r = rsqrtf(var + 1e-6f);
    bf16_t* orow = out + (size_t)n * 768;
    orow[tid]       = (bf16_t)((x0 - mu) * r * g[tid]       + b[tid]);
    orow[tid + 256] = (bf16_t)((x1 - mu) * r * g[tid + 256] + b[tid + 256]);
    orow[tid + 512] = (bf16_t)((x2 - mu) * r * g[tid + 512] + b[tid + 512]);
}

// ---------------------------------------------------------------------------
// QKV GEMM v4 = v3 with bn-fastest grid (36, 32): consecutive blocks share
// the A (token) tile; qkv_w (3.5 MB bf16) fits per-XCD L2 and is re-read
// from L2, not L3. 128(M)x64(N) tile, BK=64, async dbuf glds16 staging with
// XOR-swizzled LDS. bn: 0..11 = q-heads, 12..23 = k, 24..35 = v.
// ---------------------------------------------------------------------------
__global__ __launch_bounds__(256) void qkv_gemm(const bf16_t* __restrict__ tokb,
                                                const bf16_t* __restrict__ wq,
                                                bf16_t* __restrict__ qb,
                                                bf16_t* __restrict__ kswz,
                                                bf16_t* __restrict__ vswz) {
    const int bn = blockIdx.x;   // 36 n-tiles (64 cols = one head of q/k/v)
    const int bm = blockIdx.y;   // 32 m-tiles (128 tokens)
    const int tid = threadIdx.x;
    const int wid = tid >> 6, lane = tid & 63;
    const int ln = lane & 15, quad = lane >> 4;
    const int wm = wid & 1, wn = wid >> 1;

    __shared__ bf16_t Asw[2][8192];   // 128 rows x 8 chunks x 8 bf16
    __shared__ bf16_t Bsw[2][4096];   // 64 rows x 8 chunks

    f32x4 acc[4][2];
    #pragma unroll
    for (int sm = 0; sm < 4; sm++)
        #pragma unroll
        for (int sn = 0; sn < 2; sn++) acc[sm][sn] = {0.f, 0.f, 0.f, 0.f};

    // staging: per wave, A chunks [wid*256, +256) (4 issues), B [wid*128, +128) (2)
    auto stage = [&](int kb0, int buf) {
        #pragma unroll
        for (int i = 0; i < 4; i++) {
            int L = wid * 256 + i * 64 + lane;
            int r = L >> 3, c = L & 7;
            int gc = c ^ (r & 7);
            glds16(tokb + (size_t)(bm * 128 + r) * 768 + kb0 + gc * 8,
                   Asw[buf] + (wid * 256 + i * 64) * 8);
        }
        #pragma unroll
        for (int i = 0; i < 2; i++) {
            int L = wid * 128 + i * 64 + lane;
            int r = L >> 3, c = L & 7;
            int gc = c ^ (r & 7);
            glds16(wq + (size_t)(bn * 64 + r) * 768 + kb0 + gc * 8,
                   Bsw[buf] + (wid * 128 + i * 64) * 8);
        }
    };

    auto compute = [&](const bf16_t* Ab, const bf16_t* Bb) {
        #pragma unroll
        for (int kk = 0; kk < 2; kk++) {
            const int c = (kk * 4 + quad) ^ (ln & 7);
            bf16x8 af[4], bfr[2];
            #pragma unroll
            for (int sm = 0; sm < 4; sm++) {
                int row = wm * 64 + sm * 16 + ln;
                af[sm] = *(const bf16x8*)(Ab + (row * 8 + c) * 8);
            }
            #pragma unroll
            for (int sn = 0; sn < 2; sn++) {
                int row = wn * 32 + sn * 16 + ln;
                bfr[sn] = *(const bf16x8*)(Bb + (row * 8 + c) * 8);
            }
            #pragma unroll
            for (int sm = 0; sm < 4; sm++)
                #pragma unroll
                for (int sn = 0; sn < 2; sn++)
                    acc[sm][sn] = __builtin_amdgcn_mfma_f32_16x16x32_bf16(af[sm], bfr[sn], acc[sm][sn], 0, 0, 0);
        }
    };

    stage(0, 0);

    for (int s = 0; s < 12; s += 2) {
        __builtin_amdgcn_s_barrier();                 // prev reads of buf1 done
        stage((s + 1) * 64, 1);
        __builtin_amdgcn_s_waitcnt(0x0F76);           // vmcnt(6): buf0 resident
        __builtin_amdgcn_s_barrier();
        compute(Asw[0], Bsw[0]);
        __builtin_amdgcn_s_barrier();                 // prev reads of buf0 done
        if (s + 2 < 12) {
            stage((s + 2) * 64, 0);
            __builtin_amdgcn_s_waitcnt(0x0F76);       // vmcnt(6)
        } else {
            __builtin_amdgcn_s_waitcnt(0x0F70);       // vmcnt(0)
        }
        __builtin_amdgcn_s_barrier();
        compute(Asw[1], Bsw[1]);
    }

    const int sidx = bn / 12;                  // 0=q 1=k 2=v (block-uniform)
    const int head = bn % 12;
    #pragma unroll
    for (int sn = 0; sn < 2; sn++) {
        int dc = wn * 32 + sn * 16 + ln;       // 0..63 within head
        #pragma unroll
        for (int sm = 0; sm < 4; sm++) {
            #pragma unroll
            for (int r = 0; r < 4; r++) {
                int m = bm * 128 + wm * 64 + sm * 16 + quad * 4 + r;   // token = key
                float v = acc[sm][sn][r];
                if (sidx == 0) {
                    qb[((size_t)(head * 4096 + m)) * 64 + dc] = (bf16_t)(v * QSCALE);
                } else if (sidx == 1) {
                    bf16_t val = (bf16_t)v;
                    int kt = m >> 6, sb = (m >> 4) & 3, lnk = m & 15;
                    int half = dc >> 5, quadk = (dc >> 3) & 3, j = dc & 7;
                    int l = quadk * 16 + lnk;
                    kswz[((size_t)(head * 64 + kt)) * 4096 + sb * 1024 + half * 512 + l * 8 + j] = val;
                } else {
                    bf16_t val = (bf16_t)v;
                    int kt = m >> 6, keyl = m & 63;
                    int sblk = keyl >> 4;
                    int mm = sblk >> 1, tb = sblk & 1;
                    int w16 = keyl & 15, qv = w16 >> 2, jj = w16 & 3;
                    int jp = tb * 4 + jj;
                    int db = dc >> 4, lnv = dc & 15;
                    int l = qv * 16 + lnv;
                    vswz[((size_t)(head * 64 + kt)) * 4096 + ((mm * 4 + db) * 64 + l) * 8 + jp] = val;
                }
            }
        }
    }
}

// ---------------------------------------------------------------------------
// Attention: split-K=2, no atomics, async dbuf glds pipeline, raw v_exp_f32,
// perm-truncated P pack, l via ones-MFMA.
// Grid: (32, 12, 2), 256 threads = 4 waves x 32 q.
// ---------------------------------------------------------------------------
__global__ __launch_bounds__(256, 2) void attn_partial(const bf16_t* __restrict__ qbuf,
                                                       const bf16_t* __restrict__ kswz,
                                                       const bf16_t* __restrict__ vswz,
                                                       float* __restrict__ raw0,
                                                       float* __restrict__ raw1,
                                                       float* __restrict__ l_part) {
    const int h = blockIdx.y;
    const int chunk = blockIdx.z;
    const int tid = threadIdx.x;
    const int wid = tid >> 6;           // 0..3
    const int lane = tid & 63;
    const int ln = lane & 15, quad = lane >> 4;
    const int q0 = blockIdx.x * 128;

    __shared__ bf16_t Kf[2][4096];
    __shared__ bf16_t Vf[2][4096];

    // Q B-frags for this wave's two 16-query groups
    bf16x8 qf[2][2];
    #pragma unroll
    for (int g = 0; g < 2; g++) {
        const int q0g = q0 + wid * 32 + g * 16;
        const bf16_t* qrow = qbuf + ((size_t)h * 4096 + q0g + ln) * 64;
        qf[g][0] = *(const bf16x8*)(qrow + quad * 8);
        qf[g][1] = *(const bf16x8*)(qrow + 32 + quad * 8);
    }

    // all-ones A fragment for the l row-sum MFMA
    bf16x8 ones;
    #pragma unroll
    for (int i = 0; i < 8; i++) ones[i] = (bf16_t)1.0f;

    const bf16_t* kg = kswz + (size_t)h * 64 * 4096 + (size_t)chunk * 32 * 4096;
    const bf16_t* vg = vswz + (size_t)h * 64 * 4096 + (size_t)chunk * 32 * 4096;

    f32x4 accO[2][4];
    f32x4 accL[2];
    #pragma unroll
    for (int g = 0; g < 2; g++) {
        accL[g] = {0.f, 0.f, 0.f, 0.f};
        #pragma unroll
        for (int d = 0; d < 4; d++) accO[g][d] = {0.f, 0.f, 0.f, 0.f};
    }

    // stage one 8KB K + 8KB V tile; 4 waves cover it: 2 K + 2 V glds per wave
    auto stage = [&](int tile, int buf) {
        const bf16_t* kt_g = kg + (size_t)tile * 4096;
        const bf16_t* vt_g = vg + (size_t)tile * 4096;
        #pragma unroll
        for (int i = 0; i < 2; i++) {
            glds16(kt_g + wid * 1024 + i * 512 + lane * 8, &Kf[buf][wid * 1024 + i * 512]);
            glds16(vt_g + wid * 1024 + i * 512 + lane * 8, &Vf[buf][wid * 1024 + i * 512]);
        }
    };

    auto compute = [&](const bf16_t* Kb, const bf16_t* Vb) {
        #pragma unroll
        for (int m = 0; m < 2; m++) {        // m-pair = 32 keys
            bf16x8 vf[4];
            #pragma unroll
            for (int db = 0; db < 4; db++)
                vf[db] = *(const bf16x8*)(Vb + m * 2048 + db * 512 + lane * 8);
            bf16x8 kfa0 = *(const bf16x8*)(Kb + (2 * m) * 1024 + lane * 8);
            bf16x8 kfa1 = *(const bf16x8*)(Kb + (2 * m) * 1024 + 512 + lane * 8);
            bf16x8 kfb0 = *(const bf16x8*)(Kb + (2 * m + 1) * 1024 + lane * 8);
            bf16x8 kfb1 = *(const bf16x8*)(Kb + (2 * m + 1) * 1024 + 512 + lane * 8);
            #pragma unroll
            for (int g = 0; g < 2; g++) {
                f32x4 z = {0.f, 0.f, 0.f, 0.f};
                f32x4 SA = __builtin_amdgcn_mfma_f32_16x16x32_bf16(kfa0, qf[g][0], z, 0, 0, 0);
                SA = __builtin_amdgcn_mfma_f32_16x16x32_bf16(kfa1, qf[g][1], SA, 0, 0, 0);
                f32x4 SB = __builtin_amdgcn_mfma_f32_16x16x32_bf16(kfb0, qf[g][0], z, 0, 0, 0);
                SB = __builtin_amdgcn_mfma_f32_16x16x32_bf16(kfb1, qf[g][1], SB, 0, 0, 0);

                float e0 = hwexp2(SA[0]), e1 = hwexp2(SA[1]), e2 = hwexp2(SA[2]), e3 = hwexp2(SA[3]);
                float e4 = hwexp2(SB[0]), e5 = hwexp2(SB[1]), e6 = hwexp2(SB[2]), e7 = hwexp2(SB[3]);
                uint4v u = {pack_trunc(e0, e1), pack_trunc(e2, e3),
                            pack_trunc(e4, e5), pack_trunc(e6, e7)};
                bf16x8 pb = __builtin_bit_cast(bf16x8, u);
                accL[g] = __builtin_amdgcn_mfma_f32_16x16x32_bf16(ones, pb, accL[g], 0, 0, 0);
                #pragma unroll
                for (int db = 0; db < 4; db++)
                    accO[g][db] = __builtin_amdgcn_mfma_f32_16x16x32_bf16(vf[db], pb, accO[g][db], 0, 0, 0);
            }
        }
    };

    stage(0, 0);

    for (int kt = 0; kt < 32; kt += 2) {
        __builtin_amdgcn_s_barrier();                 // prev reads of buf1 done
        stage(kt + 1, 1);
        __builtin_amdgcn_s_waitcnt(0x0F74);           // vmcnt(4): tile kt resident
        __builtin_amdgcn_s_barrier();
        compute(&Kf[0][0], &Vf[0][0]);
        __builtin_amdgcn_s_barrier();                 // prev reads of buf0 done
        if (kt + 2 < 32) {
            stage(kt + 2, 0);
            __builtin_amdgcn_s_waitcnt(0x0F74);       // vmcnt(4)
        } else {
            __builtin_amdgcn_s_waitcnt(0x0F70);       // vmcnt(0)
        }
        __builtin_amdgcn_s_barrier();
        compute(&Kf[1][0], &Vf[1][0]);
    }

    float* base = chunk ? raw1 : raw0;
    #pragma unroll
    for (int g = 0; g < 2; g++) {
        // every lane's accL[g][0] holds l[q=ln] (rows identical for ones-A)
        const int qg = q0 + wid * 32 + g * 16 + ln;
        if (quad == 0) l_part[(size_t)chunk * 49152 + h * 4096 + qg] = accL[g][0];
        float* op = base + (size_t)qg * 768 + h * 64 + quad * 4;
        #pragma unroll
        for (int db = 0; db < 4; db++)
            *(f32x4*)(op + db * 16) = accO[g][db];
    }
}

// ---------------------------------------------------------------------------
// Normalize + combine: out[q,c] = (raw0[q,c] + raw1[q,c]) / (l0[h][q]+l1[h][q])
// raw1 aliases out (d_out scratch) — element-wise read-then-write, safe.
// ---------------------------------------------------------------------------
__global__ __launch_bounds__(256) void norm_kernel(const float* __restrict__ raw0,
                                                   const float* __restrict__ raw1,
                                                   const float* __restrict__ l_part,
                                                   float* __restrict__ out) {
    const int q = blockIdx.x;
    const int tid = threadIdx.x;
    __shared__ float linv[12];
    if (tid < 12)
        linv[tid] = 1.0f / (l_part[tid * 4096 + q] + l_part[49152 + tid * 4096 + q]);
    __syncthreads();
    #pragma unroll
    for (int t = 0; t < 3; t++) {
        int c = tid + t * 256;
        size_t idx = (size_t)q * 768 + c;
        out[idx] = (raw0[idx] + raw1[idx]) * linv[c >> 6];
    }
}

// ---------------------------------------------------------------------------
extern "C" void kernel_launch(void* const* d_in, const int* in_sizes, int n_in,
                              void* d_out, int out_size, void* d_ws, size_t ws_size,
                              hipStream_t stream) {
    const float* x      = (const float*)d_in[0];
    const float* proj_w = (const float*)d_in[1];
    const float* proj_b = (const float*)d_in[2];
    const float* ln_g   = (const float*)d_in[3];
    const float* ln_b   = (const float*)d_in[4];
    const float* qkv_w  = (const float*)d_in[5];
    float* out = (float*)d_out;

    char* ws = (char*)d_ws;
    float*  tok_pre = (float*)(ws + 0);              // 12,582,912 B (reused: raw0)
    bf16_t* tok_b   = (bf16_t*)(ws + 12582912);      //  6,291,456 B
    bf16_t* pw_b    = (bf16_t*)(ws + 18874368);      //    393,216 B (reused: l_part)
    bf16_t* qw_b    = (bf16_t*)(ws + 19267584);      //  3,538,944 B
    bf16_t* qbuf    = (bf16_t*)(ws + 22806528);      //  6,291,456 B
    bf16_t* kswz    = (bf16_t*)(ws + 29097984);      //  6,291,456 B
    bf16_t* vswz    = (bf16_t*)(ws + 35389440);      //  6,291,456 B (total ~41.7 MB)
    float*  raw0    = tok_pre;                       // dead after ln_kernel
    float*  raw1    = out;                           // d_out used as chunk-1 scratch
    float*  l_part  = (float*)pw_b;                  // never used as pw_b anymore

    cvt_kernel<<<1728, 256, 0, stream>>>(qkv_w, qw_b, 442368);
    patch_gemm<<<dim3(12, 64), 256, 0, stream>>>(x, proj_w, proj_b, tok_pre);
    ln_kernel<<<4096, 256, 0, stream>>>(tok_pre, ln_g, ln_b, tok_b);
    qkv_gemm<<<dim3(36, 32), 256, 0, stream>>>(tok_b, qw_b, qbuf, kswz, vswz);
    attn_partial<<<dim3(32, 12, 2), 256, 0, stream>>>(qbuf, kswz, vswz, raw0, raw1, l_part);
    norm_kernel<<<4096, 256, 0, stream>>>(raw0, raw1, l_part, out);
}